// Round 1
// baseline (514.477 us; speedup 1.0000x reference)
//
#include <hip/hip_runtime.h>
#include <hip/hip_bf16.h>
#include <cstdint>

using bf16x8 = __attribute__((ext_vector_type(8))) __bf16;
using f32x4  = __attribute__((ext_vector_type(4))) float;

#define LOG2E 1.4426950408889634f

// ---------------------------------------------------------------------------
// RMSNorm: one block (256 threads) per row of 1024 fp32 -> bf16
// ---------------------------------------------------------------------------
__global__ __launch_bounds__(256) void rmsnorm_kernel(const float* __restrict__ x,
                                                      const float* __restrict__ w,
                                                      __bf16* __restrict__ xn) {
    const int row = blockIdx.x;
    const float4 v = reinterpret_cast<const float4*>(x + (size_t)row * 1024)[threadIdx.x];
    float ss = v.x * v.x + v.y * v.y + v.z * v.z + v.w * v.w;
#pragma unroll
    for (int i = 1; i < 64; i <<= 1) ss += __shfl_xor(ss, i);
    __shared__ float part[4];
    if ((threadIdx.x & 63) == 0) part[threadIdx.x >> 6] = ss;
    __syncthreads();
    const float total = part[0] + part[1] + part[2] + part[3];
    const float scale = rsqrtf(total * (1.0f / 1024.0f) + 1.1920929e-07f);
    const float4 wv = reinterpret_cast<const float4*>(w)[threadIdx.x];
    union { __bf16 h[4]; uint2 u; } pk;
    pk.h[0] = (__bf16)(v.x * scale * wv.x);
    pk.h[1] = (__bf16)(v.y * scale * wv.y);
    pk.h[2] = (__bf16)(v.z * scale * wv.z);
    pk.h[3] = (__bf16)(v.w * scale * wv.w);
    reinterpret_cast<uint2*>(xn + (size_t)row * 1024)[threadIdx.x] = pk.u;
}

// ---------------------------------------------------------------------------
// Transpose + cast: in (K x N) fp32 row-major -> out (N x K) bf16 row-major
// ---------------------------------------------------------------------------
__global__ void transpose_cast_kernel(const float* __restrict__ in,
                                      __bf16* __restrict__ out, int K, int N) {
    __shared__ float tile[32][33];
    const int n0 = blockIdx.x * 32, k0 = blockIdx.y * 32;
#pragma unroll
    for (int r = threadIdx.y; r < 32; r += 8)
        tile[r][threadIdx.x] = in[(size_t)(k0 + r) * N + n0 + threadIdx.x];
    __syncthreads();
#pragma unroll
    for (int r = threadIdx.y; r < 32; r += 8)
        out[(size_t)(n0 + r) * K + k0 + threadIdx.x] = (__bf16)tile[threadIdx.x][r];
}

// ---------------------------------------------------------------------------
// GEMM: C(MxN) = A(MxK) @ Bt(NxK)^T, bf16 inputs, fp32 accum.
// 128x128 tile, BK=32, 256 threads = 4 waves (2x2), 4x4 16x16 frags per wave.
// ---------------------------------------------------------------------------
template <typename OutT>
__global__ __launch_bounds__(256) void gemm_bt(const __bf16* __restrict__ A,
                                               const __bf16* __restrict__ Bt,
                                               OutT* __restrict__ C,
                                               int M, int N, int K) {
    __shared__ __align__(16) __bf16 As[128][32];
    __shared__ __align__(16) __bf16 Bs[128][32];
    const int bm = blockIdx.y, bn = blockIdx.x;
    const int tid = threadIdx.x;
    const int w = tid >> 6, l = tid & 63, lg = l >> 4, lr = l & 15;
    const int wr = w >> 1, wc = w & 1;
    const __bf16* Ab = A + (size_t)(bm * 128) * K;
    const __bf16* Bb = Bt + (size_t)(bn * 128) * K;
    f32x4 acc[4][4] = {};
    for (int k0 = 0; k0 < K; k0 += 32) {
#pragma unroll
        for (int j = 0; j < 2; ++j) {
            const int c = tid * 2 + j;            // 0..511 chunks of 8 elems
            const int row = c >> 2, col = (c & 3) * 8;
            *reinterpret_cast<bf16x8*>(&As[row][col]) =
                *reinterpret_cast<const bf16x8*>(Ab + (size_t)row * K + k0 + col);
            *reinterpret_cast<bf16x8*>(&Bs[row][col]) =
                *reinterpret_cast<const bf16x8*>(Bb + (size_t)row * K + k0 + col);
        }
        __syncthreads();
        bf16x8 af[4], bfr[4];
#pragma unroll
        for (int m = 0; m < 4; ++m)
            af[m] = *reinterpret_cast<const bf16x8*>(&As[wr * 64 + m * 16 + lr][lg * 8]);
#pragma unroll
        for (int nn = 0; nn < 4; ++nn)
            bfr[nn] = *reinterpret_cast<const bf16x8*>(&Bs[wc * 64 + nn * 16 + lr][lg * 8]);
#pragma unroll
        for (int m = 0; m < 4; ++m)
#pragma unroll
            for (int nn = 0; nn < 4; ++nn)
                acc[m][nn] = __builtin_amdgcn_mfma_f32_16x16x32_bf16(af[m], bfr[nn],
                                                                     acc[m][nn], 0, 0, 0);
        __syncthreads();
    }
#pragma unroll
    for (int m = 0; m < 4; ++m) {
        const int rg = bm * 128 + wr * 64 + m * 16 + 4 * lg;
#pragma unroll
        for (int nn = 0; nn < 4; ++nn) {
            const int cg = bn * 128 + wc * 64 + nn * 16 + lr;
#pragma unroll
            for (int r = 0; r < 4; ++r)
                C[(size_t)(rg + r) * N + cg] = (OutT)acc[m][nn][r];
        }
    }
}

// ---------------------------------------------------------------------------
// RoPE in-place on qkv [8192][1536]; q also scaled by d^-0.5 * log2(e)
// (so attention softmax can use exp2). 32 threads per (b,h,n) triple.
// ---------------------------------------------------------------------------
__global__ __launch_bounds__(256) void rope_kernel(__bf16* __restrict__ qkv,
                                                   const float* __restrict__ rot) {
    const int t = blockIdx.x * 8 + (threadIdx.x >> 5);   // 0..65535  (b,h,pos)
    const int d = threadIdx.x & 31;
    const int pos = t & 4095;
    const int h = (t >> 12) & 7;
    const int b = t >> 15;
    float s0, c0, s1, c1;
    sincosf(rot[pos * 64 + d], &s0, &c0);
    sincosf(rot[pos * 64 + d + 32], &s1, &c1);
    __bf16* qp = qkv + ((size_t)b * 4096 + pos) * 1536 + h * 64;
    const float qs = 0.125f * LOG2E;
    {
        const float a = (float)qp[d], bb = (float)qp[d + 32];
        qp[d]      = (__bf16)((a * c0 - bb * s0) * qs);
        qp[d + 32] = (__bf16)((bb * c1 + a * s1) * qs);
    }
    __bf16* kp = qp + 512;
    {
        const float a = (float)kp[d], bb = (float)kp[d + 32];
        kp[d]      = (__bf16)(a * c0 - bb * s0);
        kp[d + 32] = (__bf16)(bb * c1 + a * s1);
    }
}

// ---------------------------------------------------------------------------
// Causal flash attention. Grid: (n/64, b*h). Block: 256 = 4 waves.
// Wave w owns q-rows [q0+16w, q0+16w+16). K/V tiles of 32 staged in LDS.
// qkv layout: [b*4096+pos][1536] with q at col 0, k at 512, v at 1024 (+h*64).
// Softmax in exp2 domain (log2e folded into q).
// ---------------------------------------------------------------------------
__global__ __launch_bounds__(256) void attn_kernel(const __bf16* __restrict__ qkv,
                                                   __bf16* __restrict__ attn_out) {
    const int bh = blockIdx.y;
    const int b = bh >> 3, h = bh & 7;
    const int q0 = blockIdx.x * 64;
    const int tid = threadIdx.x;
    const int w = tid >> 6, l = tid & 63, lg = l >> 4, lr = l & 15;

    __shared__ __align__(16) __bf16 Ks[32][72];   // [j][d], padded 64->72
    __shared__ __align__(16) __bf16 Vt[64][40];   // [d][j], padded 32->40
    __shared__ __align__(16) __bf16 Pl[4][16][40]; // per-wave P tile

    const size_t rs = 1536;
    const __bf16* qbase = qkv + ((size_t)b * 4096) * rs + h * 64;
    const __bf16* kbase = qbase + 512;
    const __bf16* vbase = qbase + 1024;
    const int wq0 = q0 + w * 16;

    bf16x8 Qf[2];
    {
        const __bf16* qp = qbase + (size_t)(wq0 + lr) * rs + lg * 8;
        Qf[0] = *reinterpret_cast<const bf16x8*>(qp);
        Qf[1] = *reinterpret_cast<const bf16x8*>(qp + 32);
    }

    f32x4 Of[4] = {};
    float m_r[4], l_r[4];
#pragma unroll
    for (int r = 0; r < 4; ++r) { m_r[r] = -1e30f; l_r[r] = 0.0f; }

    const int nkt = (q0 + 64) / 32;
    for (int kt = 0; kt < nkt; ++kt) {
        const int k0 = kt * 32;
        {   // stage K tile and transposed V tile
            const int r = tid >> 3;
            const int c = (tid & 7) * 8;
            const bf16x8 kv = *reinterpret_cast<const bf16x8*>(kbase + (size_t)(k0 + r) * rs + c);
            *reinterpret_cast<bf16x8*>(&Ks[r][c]) = kv;
            const bf16x8 vv = *reinterpret_cast<const bf16x8*>(vbase + (size_t)(k0 + r) * rs + c);
#pragma unroll
            for (int i = 0; i < 8; ++i) Vt[c + i][r] = vv[i];
        }
        __syncthreads();

        if (k0 <= wq0 + 15) {
            // S = Q @ K^T   (16 q-rows x 32 keys)
            f32x4 S[2] = {};
#pragma unroll
            for (int jt = 0; jt < 2; ++jt) {
                const bf16x8 K0 = *reinterpret_cast<const bf16x8*>(&Ks[jt * 16 + lr][lg * 8]);
                const bf16x8 K1 = *reinterpret_cast<const bf16x8*>(&Ks[jt * 16 + lr][32 + lg * 8]);
                S[jt] = __builtin_amdgcn_mfma_f32_16x16x32_bf16(Qf[0], K0, S[jt], 0, 0, 0);
                S[jt] = __builtin_amdgcn_mfma_f32_16x16x32_bf16(Qf[1], K1, S[jt], 0, 0, 0);
            }
            // causal mask
#pragma unroll
            for (int jt = 0; jt < 2; ++jt)
#pragma unroll
                for (int r = 0; r < 4; ++r) {
                    const int i_g = wq0 + 4 * lg + r;
                    const int j_g = k0 + jt * 16 + lr;
                    if (j_g > i_g) S[jt][r] = -1e30f;
                }
            // online softmax (exp2 domain), rows live across 16-lane groups
            float P0[4], P1[4];
#pragma unroll
            for (int r = 0; r < 4; ++r) {
                float mx = fmaxf(S[0][r], S[1][r]);
                mx = fmaxf(mx, __shfl_xor(mx, 1));
                mx = fmaxf(mx, __shfl_xor(mx, 2));
                mx = fmaxf(mx, __shfl_xor(mx, 4));
                mx = fmaxf(mx, __shfl_xor(mx, 8));
                const float mn = fmaxf(m_r[r], mx);
                const float p0 = exp2f(S[0][r] - mn);
                const float p1 = exp2f(S[1][r] - mn);
                P0[r] = p0; P1[r] = p1;
                float s = p0 + p1;
                s += __shfl_xor(s, 1);
                s += __shfl_xor(s, 2);
                s += __shfl_xor(s, 4);
                s += __shfl_xor(s, 8);
                const float alpha = exp2f(m_r[r] - mn);
                l_r[r] = l_r[r] * alpha + s;
                m_r[r] = mn;
#pragma unroll
                for (int dt = 0; dt < 4; ++dt) Of[dt][r] *= alpha;
            }
            // P -> LDS (re-layout for MFMA A operand)
#pragma unroll
            for (int r = 0; r < 4; ++r) {
                Pl[w][4 * lg + r][lr]      = (__bf16)P0[r];
                Pl[w][4 * lg + r][16 + lr] = (__bf16)P1[r];
            }
            asm volatile("s_waitcnt lgkmcnt(0)" ::: "memory");
            // O += P @ V
            const bf16x8 Pf = *reinterpret_cast<const bf16x8*>(&Pl[w][lr][lg * 8]);
#pragma unroll
            for (int dt = 0; dt < 4; ++dt) {
                const bf16x8 Vf = *reinterpret_cast<const bf16x8*>(&Vt[dt * 16 + lr][lg * 8]);
                Of[dt] = __builtin_amdgcn_mfma_f32_16x16x32_bf16(Pf, Vf, Of[dt], 0, 0, 0);
            }
        }
        __syncthreads();
    }
    // epilogue: O / l, write bf16 to attn_out[b][n][h*64+d]
#pragma unroll
    for (int r = 0; r < 4; ++r) {
        const float inv = 1.0f / l_r[r];
        const int i_g = wq0 + 4 * lg + r;
        __bf16* op = attn_out + ((size_t)b * 4096 + i_g) * 512 + h * 64;
#pragma unroll
        for (int dt = 0; dt < 4; ++dt)
            op[dt * 16 + lr] = (__bf16)(Of[dt][r] * inv);
    }
}

// ---------------------------------------------------------------------------
extern "C" void kernel_launch(void* const* d_in, const int* in_sizes, int n_in,
                              void* d_out, int out_size, void* d_ws, size_t ws_size,
                              hipStream_t stream) {
    (void)in_sizes; (void)n_in; (void)out_size; (void)ws_size;
    const float* x    = (const float*)d_in[0];
    const float* rot  = (const float*)d_in[1];
    const float* rmsw = (const float*)d_in[2];
    const float* wqkv = (const float*)d_in[3];
    const float* wout = (const float*)d_in[4];
    float* out = (float*)d_out;

    char* ws = (char*)d_ws;
    __bf16* xn    = (__bf16*)ws;                       // 8192*1024*2 = 16,777,216 B
    __bf16* wqkvt = (__bf16*)(ws + 16777216);          // 1536*1024*2 =  3,145,728 B
    __bf16* woutt = (__bf16*)(ws + 16777216 + 3145728);// 1024*512*2  =  1,048,576 B
    __bf16* aout  = (__bf16*)(ws + 16777216 + 3145728 + 1048576); // 8192*512*2 = 8,388,608 B
    // qkv scratch lives in d_out (33.5 MB >= 25.2 MB needed); overwritten by final GEMM.
    __bf16* qkv   = (__bf16*)d_out;

    rmsnorm_kernel<<<8192, 256, 0, stream>>>(x, rmsw, xn);
    transpose_cast_kernel<<<dim3(48, 32), dim3(32, 8), 0, stream>>>(wqkv, wqkvt, 1024, 1536);
    transpose_cast_kernel<<<dim3(32, 16), dim3(32, 8), 0, stream>>>(wout, woutt, 512, 1024);
    gemm_bt<__bf16><<<dim3(12, 64), 256, 0, stream>>>(xn, wqkvt, qkv, 8192, 1536, 1024);
    rope_kernel<<<8192, 256, 0, stream>>>(qkv, rot);
    attn_kernel<<<dim3(64, 16), 256, 0, stream>>>(qkv, aout);
    gemm_bt<float><<<dim3(8, 64), 256, 0, stream>>>(aout, woutt, out, 8192, 1024, 512);
}

// Round 2
// 265.838 us; speedup vs baseline: 1.9353x; 1.9353x over previous
//
#include <hip/hip_runtime.h>
#include <hip/hip_bf16.h>
#include <cstdint>

using bf16x8 = __attribute__((ext_vector_type(8))) __bf16;
using f32x4  = __attribute__((ext_vector_type(4))) float;

#define LOG2E 1.4426950408889634f

// ---------------------------------------------------------------------------
// RMSNorm: one block (256 threads) per row of 1024 fp32 -> bf16
// ---------------------------------------------------------------------------
__global__ __launch_bounds__(256) void rmsnorm_kernel(const float* __restrict__ x,
                                                      const float* __restrict__ w,
                                                      __bf16* __restrict__ xn) {
    const int row = blockIdx.x;
    const float4 v = reinterpret_cast<const float4*>(x + (size_t)row * 1024)[threadIdx.x];
    float ss = v.x * v.x + v.y * v.y + v.z * v.z + v.w * v.w;
#pragma unroll
    for (int i = 1; i < 64; i <<= 1) ss += __shfl_xor(ss, i);
    __shared__ float part[4];
    if ((threadIdx.x & 63) == 0) part[threadIdx.x >> 6] = ss;
    __syncthreads();
    const float total = part[0] + part[1] + part[2] + part[3];
    const float scale = rsqrtf(total * (1.0f / 1024.0f) + 1.1920929e-07f);
    const float4 wv = reinterpret_cast<const float4*>(w)[threadIdx.x];
    union { __bf16 h[4]; uint2 u; } pk;
    pk.h[0] = (__bf16)(v.x * scale * wv.x);
    pk.h[1] = (__bf16)(v.y * scale * wv.y);
    pk.h[2] = (__bf16)(v.z * scale * wv.z);
    pk.h[3] = (__bf16)(v.w * scale * wv.w);
    reinterpret_cast<uint2*>(xn + (size_t)row * 1024)[threadIdx.x] = pk.u;
}

// ---------------------------------------------------------------------------
// Transpose + cast: in (K x N) fp32 row-major -> out (N x K) bf16 row-major
// ---------------------------------------------------------------------------
__global__ void transpose_cast_kernel(const float* __restrict__ in,
                                      __bf16* __restrict__ out, int K, int N) {
    __shared__ float tile[32][33];
    const int n0 = blockIdx.x * 32, k0 = blockIdx.y * 32;
#pragma unroll
    for (int r = threadIdx.y; r < 32; r += 8)
        tile[r][threadIdx.x] = in[(size_t)(k0 + r) * N + n0 + threadIdx.x];
    __syncthreads();
#pragma unroll
    for (int r = threadIdx.y; r < 32; r += 8)
        out[(size_t)(n0 + r) * K + k0 + threadIdx.x] = (__bf16)tile[threadIdx.x][r];
}

// ---------------------------------------------------------------------------
// GEMM: C(MxN) = A(MxK) @ Bt(NxK)^T, bf16 inputs, fp32 accum.
// 128x128 tile, BK=32, 256 threads = 4 waves (2x2), 4x4 16x16 frags per wave.
// ---------------------------------------------------------------------------
template <typename OutT>
__global__ __launch_bounds__(256) void gemm_bt(const __bf16* __restrict__ A,
                                               const __bf16* __restrict__ Bt,
                                               OutT* __restrict__ C,
                                               int M, int N, int K) {
    __shared__ __align__(16) __bf16 As[128][32];
    __shared__ __align__(16) __bf16 Bs[128][32];
    const int bm = blockIdx.y, bn = blockIdx.x;
    const int tid = threadIdx.x;
    const int w = tid >> 6, l = tid & 63, lg = l >> 4, lr = l & 15;
    const int wr = w >> 1, wc = w & 1;
    const __bf16* Ab = A + (size_t)(bm * 128) * K;
    const __bf16* Bb = Bt + (size_t)(bn * 128) * K;
    f32x4 acc[4][4] = {};
    for (int k0 = 0; k0 < K; k0 += 32) {
#pragma unroll
        for (int j = 0; j < 2; ++j) {
            const int c = tid * 2 + j;            // 0..511 chunks of 8 elems
            const int row = c >> 2, col = (c & 3) * 8;
            *reinterpret_cast<bf16x8*>(&As[row][col]) =
                *reinterpret_cast<const bf16x8*>(Ab + (size_t)row * K + k0 + col);
            *reinterpret_cast<bf16x8*>(&Bs[row][col]) =
                *reinterpret_cast<const bf16x8*>(Bb + (size_t)row * K + k0 + col);
        }
        __syncthreads();
        bf16x8 af[4], bfr[4];
#pragma unroll
        for (int m = 0; m < 4; ++m)
            af[m] = *reinterpret_cast<const bf16x8*>(&As[wr * 64 + m * 16 + lr][lg * 8]);
#pragma unroll
        for (int nn = 0; nn < 4; ++nn)
            bfr[nn] = *reinterpret_cast<const bf16x8*>(&Bs[wc * 64 + nn * 16 + lr][lg * 8]);
#pragma unroll
        for (int m = 0; m < 4; ++m)
#pragma unroll
            for (int nn = 0; nn < 4; ++nn)
                acc[m][nn] = __builtin_amdgcn_mfma_f32_16x16x32_bf16(af[m], bfr[nn],
                                                                     acc[m][nn], 0, 0, 0);
        __syncthreads();
    }
#pragma unroll
    for (int m = 0; m < 4; ++m) {
        const int rg = bm * 128 + wr * 64 + m * 16 + 4 * lg;
#pragma unroll
        for (int nn = 0; nn < 4; ++nn) {
            const int cg = bn * 128 + wc * 64 + nn * 16 + lr;
#pragma unroll
            for (int r = 0; r < 4; ++r)
                C[(size_t)(rg + r) * N + cg] = (OutT)acc[m][nn][r];
        }
    }
}

// ---------------------------------------------------------------------------
// RoPE in-place on qkv [8192][1536]; q also scaled by d^-0.5 * log2(e)
// ---------------------------------------------------------------------------
__global__ __launch_bounds__(256) void rope_kernel(__bf16* __restrict__ qkv,
                                                   const float* __restrict__ rot) {
    const int t = blockIdx.x * 8 + (threadIdx.x >> 5);   // 0..65535  (b,h,pos)
    const int d = threadIdx.x & 31;
    const int pos = t & 4095;
    const int h = (t >> 12) & 7;
    const int b = t >> 15;
    float s0, c0, s1, c1;
    sincosf(rot[pos * 64 + d], &s0, &c0);
    sincosf(rot[pos * 64 + d + 32], &s1, &c1);
    __bf16* qp = qkv + ((size_t)b * 4096 + pos) * 1536 + h * 64;
    const float qs = 0.125f * LOG2E;
    {
        const float a = (float)qp[d], bb = (float)qp[d + 32];
        qp[d]      = (__bf16)((a * c0 - bb * s0) * qs);
        qp[d + 32] = (__bf16)((bb * c1 + a * s1) * qs);
    }
    __bf16* kp = qp + 512;
    {
        const float a = (float)kp[d], bb = (float)kp[d + 32];
        kp[d]      = (__bf16)(a * c0 - bb * s0);
        kp[d + 32] = (__bf16)(bb * c1 + a * s1);
    }
}

// ---------------------------------------------------------------------------
// Causal flash attention v2, swapped-operand MFMA layout.
// Grid: 512 blocks (1-D, XCD-swizzled, q reversed). Block: 256 = 4 waves.
// Block covers 128 q-rows (wave w owns 32), KVBLK=64.
// S^T = mfma(K, Q): lane owns qrow = 16*nt + (l&15); softmax lane-local
// except two shfl_xor(16/32) reduces. O^T = mfma(V^T, P^T), rescale lane-local.
// All LDS rows padded to 72 bf16 (144B): conflict-free b128/b64 access.
// ---------------------------------------------------------------------------
__global__ __launch_bounds__(256) void attn_kernel(const __bf16* __restrict__ qkv,
                                                   __bf16* __restrict__ attn_out) {
    const int bid = blockIdx.x;
    const int swz = (bid & 7) * 64 + (bid >> 3);   // 8 XCDs x 64 chunks
    const int bh  = swz >> 5;                      // 2 heads per XCD -> L2-resident KV
    const int qt  = 31 - (swz & 31);               // heavy blocks first
    const int b = bh >> 3, h = bh & 7;
    const int q0 = qt * 128;
    const int tid = threadIdx.x;
    const int w = tid >> 6, l = tid & 63, lg = l >> 4, lr = l & 15;
    const int wq0 = q0 + 32 * w;

    __shared__ __align__(16) __bf16 Ks[64][72];     // [j][d]
    __shared__ __align__(16) __bf16 Vt[64][72];     // [d][j]
    __shared__ __align__(16) __bf16 Pl[4][16][72];  // per-wave [qrow][j]

    const size_t rs = 1536;
    const __bf16* qbase = qkv + (size_t)b * 4096 * rs + h * 64;
    const __bf16* kbase = qbase + 512;
    const __bf16* vbase = qbase + 1024;

    // Q B-frags: Qf[nt][kh] = Q[wq0+16nt+lr][32kh + 8lg + i]
    bf16x8 Qf[2][2];
#pragma unroll
    for (int nt = 0; nt < 2; ++nt)
#pragma unroll
        for (int kh = 0; kh < 2; ++kh)
            Qf[nt][kh] = *reinterpret_cast<const bf16x8*>(
                qbase + (size_t)(wq0 + 16 * nt + lr) * rs + 32 * kh + 8 * lg);

    f32x4 O[2][4] = {};                 // O^T[d=16dt+4lg+r][qrow=16nt+lr]
    float m_[2] = {-1e30f, -1e30f};
    float l_[2] = {0.0f, 0.0f};

    const int d2 = (tid & 31) * 2;      // V staging: this thread's two d-rows
    const int jc = tid >> 5;            // and 8-key chunk

    const int nkt = 2 * qt + 2;
    for (int kt = 0; kt < nkt; ++kt) {
        const int k0 = kt * 64;
        // ---- stage K tile [64][64] row-major ----
#pragma unroll
        for (int p = 0; p < 2; ++p) {
            const int c = p * 256 + tid;
            const int row = c >> 3, col = (c & 7) * 8;
            *reinterpret_cast<bf16x8*>(&Ks[row][col]) =
                *reinterpret_cast<const bf16x8*>(kbase + (size_t)(k0 + row) * rs + col);
        }
        // ---- stage V transposed: coalesced uint column loads, b128 row writes ----
        {
            union { uint u; __bf16 h[2]; } vx;
            union { __bf16 h[8]; bf16x8 v; } ra, rb;
#pragma unroll
            for (int i = 0; i < 8; ++i) {
                vx.u = *reinterpret_cast<const uint*>(vbase + (size_t)(k0 + 8 * jc + i) * rs + d2);
                ra.h[i] = vx.h[0];
                rb.h[i] = vx.h[1];
            }
            *reinterpret_cast<bf16x8*>(&Vt[d2][8 * jc])     = ra.v;
            *reinterpret_cast<bf16x8*>(&Vt[d2 + 1][8 * jc]) = rb.v;
        }
        __syncthreads();

        if (k0 <= wq0 + 31) {
            // ---- S^T = K @ Q ----
            f32x4 S[2][4] = {};
#pragma unroll
            for (int jt = 0; jt < 4; ++jt) {
                const bf16x8 Kf0 = *reinterpret_cast<const bf16x8*>(&Ks[16 * jt + lr][8 * lg]);
                const bf16x8 Kf1 = *reinterpret_cast<const bf16x8*>(&Ks[16 * jt + lr][32 + 8 * lg]);
#pragma unroll
                for (int nt = 0; nt < 2; ++nt) {
                    S[nt][jt] = __builtin_amdgcn_mfma_f32_16x16x32_bf16(Kf0, Qf[nt][0], S[nt][jt], 0, 0, 0);
                    S[nt][jt] = __builtin_amdgcn_mfma_f32_16x16x32_bf16(Kf1, Qf[nt][1], S[nt][jt], 0, 0, 0);
                }
            }
            // V^T A-frags (wave-identical, hoisted)
            bf16x8 Vf[2][4];
#pragma unroll
            for (int s = 0; s < 2; ++s)
#pragma unroll
                for (int dt = 0; dt < 4; ++dt)
                    Vf[s][dt] = *reinterpret_cast<const bf16x8*>(&Vt[16 * dt + lr][32 * s + 8 * lg]);

#pragma unroll
            for (int nt = 0; nt < 2; ++nt) {
                if (k0 > wq0 + 16 * nt + 15) continue;   // wave-uniform skip
                const int qrow = wq0 + 16 * nt + lr;
                if (k0 + 63 > wq0 + 16 * nt) {           // diagonal tile: mask
#pragma unroll
                    for (int jt = 0; jt < 4; ++jt)
#pragma unroll
                        for (int r = 0; r < 4; ++r)
                            if (k0 + 16 * jt + 4 * lg + r > qrow) S[nt][jt][r] = -1e30f;
                }
                // online softmax (exp2 domain; log2e folded into q)
                float mx = -1e30f;
#pragma unroll
                for (int jt = 0; jt < 4; ++jt)
                    mx = fmaxf(mx, fmaxf(fmaxf(S[nt][jt][0], S[nt][jt][1]),
                                         fmaxf(S[nt][jt][2], S[nt][jt][3])));
                mx = fmaxf(mx, __shfl_xor(mx, 16));
                mx = fmaxf(mx, __shfl_xor(mx, 32));
                const float mn = fmaxf(m_[nt], mx);
                const float alpha = exp2f(m_[nt] - mn);
                m_[nt] = mn;
                float sum = 0.0f;
#pragma unroll
                for (int jt = 0; jt < 4; ++jt)
#pragma unroll
                    for (int r = 0; r < 4; ++r) {
                        S[nt][jt][r] = exp2f(S[nt][jt][r] - mn);
                        sum += S[nt][jt][r];
                    }
                sum += __shfl_xor(sum, 16);
                sum += __shfl_xor(sum, 32);
                l_[nt] = l_[nt] * alpha + sum;
#pragma unroll
                for (int dt = 0; dt < 4; ++dt) O[nt][dt] *= alpha;
                // P -> LDS (b64 packs: keys 16jt+4lg..+3 for qrow=lr)
#pragma unroll
                for (int jt = 0; jt < 4; ++jt) {
                    union { __bf16 h[4]; uint2 u; } pw;
#pragma unroll
                    for (int r = 0; r < 4; ++r) pw.h[r] = (__bf16)S[nt][jt][r];
                    *reinterpret_cast<uint2*>(&Pl[w][lr][16 * jt + 4 * lg]) = pw.u;
                }
                asm volatile("s_waitcnt lgkmcnt(0)" ::: "memory");
                __builtin_amdgcn_sched_barrier(0);
                // O^T += V^T @ P^T
#pragma unroll
                for (int s = 0; s < 2; ++s) {
                    const bf16x8 Pf = *reinterpret_cast<const bf16x8*>(&Pl[w][lr][32 * s + 8 * lg]);
#pragma unroll
                    for (int dt = 0; dt < 4; ++dt)
                        O[nt][dt] = __builtin_amdgcn_mfma_f32_16x16x32_bf16(Vf[s][dt], Pf, O[nt][dt], 0, 0, 0);
                }
            }
        }
        __syncthreads();
    }
    // epilogue: attn_out[b][qrow][h*64 + d] = O^T / l
#pragma unroll
    for (int nt = 0; nt < 2; ++nt) {
        const float inv = 1.0f / l_[nt];
        __bf16* op = attn_out + ((size_t)b * 4096 + wq0 + 16 * nt + lr) * 512 + h * 64;
#pragma unroll
        for (int dt = 0; dt < 4; ++dt)
#pragma unroll
            for (int r = 0; r < 4; ++r)
                op[16 * dt + 4 * lg + r] = (__bf16)(O[nt][dt][r] * inv);
    }
}

// ---------------------------------------------------------------------------
extern "C" void kernel_launch(void* const* d_in, const int* in_sizes, int n_in,
                              void* d_out, int out_size, void* d_ws, size_t ws_size,
                              hipStream_t stream) {
    (void)in_sizes; (void)n_in; (void)out_size; (void)ws_size;
    const float* x    = (const float*)d_in[0];
    const float* rot  = (const float*)d_in[1];
    const float* rmsw = (const float*)d_in[2];
    const float* wqkv = (const float*)d_in[3];
    const float* wout = (const float*)d_in[4];
    float* out = (float*)d_out;

    char* ws = (char*)d_ws;
    __bf16* xn    = (__bf16*)ws;                       // 16,777,216 B
    __bf16* wqkvt = (__bf16*)(ws + 16777216);          //  3,145,728 B
    __bf16* woutt = (__bf16*)(ws + 16777216 + 3145728);//  1,048,576 B
    __bf16* aout  = (__bf16*)(ws + 16777216 + 3145728 + 1048576); // 8,388,608 B
    __bf16* qkv   = (__bf16*)d_out;                    // scratch; overwritten by final GEMM

    rmsnorm_kernel<<<8192, 256, 0, stream>>>(x, rmsw, xn);
    transpose_cast_kernel<<<dim3(48, 32), dim3(32, 8), 0, stream>>>(wqkv, wqkvt, 1024, 1536);
    transpose_cast_kernel<<<dim3(32, 16), dim3(32, 8), 0, stream>>>(wout, woutt, 512, 1024);
    gemm_bt<__bf16><<<dim3(12, 64), 256, 0, stream>>>(xn, wqkvt, qkv, 8192, 1536, 1024);
    rope_kernel<<<8192, 256, 0, stream>>>(qkv, rot);
    attn_kernel<<<512, 256, 0, stream>>>(qkv, aout);
    gemm_bt<float><<<dim3(8, 64), 256, 0, stream>>>(aout, woutt, out, 8192, 1024, 512);
}

// Round 3
// 234.732 us; speedup vs baseline: 2.1918x; 1.1325x over previous
//
#include <hip/hip_runtime.h>
#include <hip/hip_bf16.h>
#include <cstdint>

using bf16x8 = __attribute__((ext_vector_type(8))) __bf16;
using f32x4  = __attribute__((ext_vector_type(4))) float;

#define LOG2E 1.4426950408889634f

// ---------------------------------------------------------------------------
// RMSNorm: one block (256 threads) per row of 1024 fp32 -> bf16
// ---------------------------------------------------------------------------
__global__ __launch_bounds__(256) void rmsnorm_kernel(const float* __restrict__ x,
                                                      const float* __restrict__ w,
                                                      __bf16* __restrict__ xn) {
    const int row = blockIdx.x;
    const float4 v = reinterpret_cast<const float4*>(x + (size_t)row * 1024)[threadIdx.x];
    float ss = v.x * v.x + v.y * v.y + v.z * v.z + v.w * v.w;
#pragma unroll
    for (int i = 1; i < 64; i <<= 1) ss += __shfl_xor(ss, i);
    __shared__ float part[4];
    if ((threadIdx.x & 63) == 0) part[threadIdx.x >> 6] = ss;
    __syncthreads();
    const float total = part[0] + part[1] + part[2] + part[3];
    const float scale = rsqrtf(total * (1.0f / 1024.0f) + 1.1920929e-07f);
    const float4 wv = reinterpret_cast<const float4*>(w)[threadIdx.x];
    union { __bf16 h[4]; uint2 u; } pk;
    pk.h[0] = (__bf16)(v.x * scale * wv.x);
    pk.h[1] = (__bf16)(v.y * scale * wv.y);
    pk.h[2] = (__bf16)(v.z * scale * wv.z);
    pk.h[3] = (__bf16)(v.w * scale * wv.w);
    reinterpret_cast<uint2*>(xn + (size_t)row * 1024)[threadIdx.x] = pk.u;
}

// ---------------------------------------------------------------------------
// Transpose + cast: in (K x N) fp32 row-major -> out (N x K) bf16 row-major
// ---------------------------------------------------------------------------
__global__ void transpose_cast_kernel(const float* __restrict__ in,
                                      __bf16* __restrict__ out, int K, int N) {
    __shared__ float tile[32][33];
    const int n0 = blockIdx.x * 32, k0 = blockIdx.y * 32;
#pragma unroll
    for (int r = threadIdx.y; r < 32; r += 8)
        tile[r][threadIdx.x] = in[(size_t)(k0 + r) * N + n0 + threadIdx.x];
    __syncthreads();
#pragma unroll
    for (int r = threadIdx.y; r < 32; r += 8)
        out[(size_t)(n0 + r) * K + k0 + threadIdx.x] = (__bf16)tile[threadIdx.x][r];
}

// ---------------------------------------------------------------------------
// GEMM: C(MxN) = A(MxK) @ Bt(NxK)^T, bf16 inputs, fp32 accum.
// 128x128 tile, BK=32, 256 threads = 4 waves (2x2), 4x4 16x16 frags per wave.
// ---------------------------------------------------------------------------
template <typename OutT>
__global__ __launch_bounds__(256) void gemm_bt(const __bf16* __restrict__ A,
                                               const __bf16* __restrict__ Bt,
                                               OutT* __restrict__ C,
                                               int M, int N, int K) {
    __shared__ __align__(16) __bf16 As[128][32];
    __shared__ __align__(16) __bf16 Bs[128][32];
    const int bm = blockIdx.y, bn = blockIdx.x;
    const int tid = threadIdx.x;
    const int w = tid >> 6, l = tid & 63, lg = l >> 4, lr = l & 15;
    const int wr = w >> 1, wc = w & 1;
    const __bf16* Ab = A + (size_t)(bm * 128) * K;
    const __bf16* Bb = Bt + (size_t)(bn * 128) * K;
    f32x4 acc[4][4] = {};
    for (int k0 = 0; k0 < K; k0 += 32) {
#pragma unroll
        for (int j = 0; j < 2; ++j) {
            const int c = tid * 2 + j;            // 0..511 chunks of 8 elems
            const int row = c >> 2, col = (c & 3) * 8;
            *reinterpret_cast<bf16x8*>(&As[row][col]) =
                *reinterpret_cast<const bf16x8*>(Ab + (size_t)row * K + k0 + col);
            *reinterpret_cast<bf16x8*>(&Bs[row][col]) =
                *reinterpret_cast<const bf16x8*>(Bb + (size_t)row * K + k0 + col);
        }
        __syncthreads();
        bf16x8 af[4], bfr[4];
#pragma unroll
        for (int m = 0; m < 4; ++m)
            af[m] = *reinterpret_cast<const bf16x8*>(&As[wr * 64 + m * 16 + lr][lg * 8]);
#pragma unroll
        for (int nn = 0; nn < 4; ++nn)
            bfr[nn] = *reinterpret_cast<const bf16x8*>(&Bs[wc * 64 + nn * 16 + lr][lg * 8]);
#pragma unroll
        for (int m = 0; m < 4; ++m)
#pragma unroll
            for (int nn = 0; nn < 4; ++nn)
                acc[m][nn] = __builtin_amdgcn_mfma_f32_16x16x32_bf16(af[m], bfr[nn],
                                                                     acc[m][nn], 0, 0, 0);
        __syncthreads();
    }
#pragma unroll
    for (int m = 0; m < 4; ++m) {
        const int rg = bm * 128 + wr * 64 + m * 16 + 4 * lg;
#pragma unroll
        for (int nn = 0; nn < 4; ++nn) {
            const int cg = bn * 128 + wc * 64 + nn * 16 + lr;
#pragma unroll
            for (int r = 0; r < 4; ++r)
                C[(size_t)(rg + r) * N + cg] = (OutT)acc[m][nn][r];
        }
    }
}

// ---------------------------------------------------------------------------
// RoPE in-place on qkv [8192][1536]; q also scaled by d^-0.5 * log2(e)
// ---------------------------------------------------------------------------
__global__ __launch_bounds__(256) void rope_kernel(__bf16* __restrict__ qkv,
                                                   const float* __restrict__ rot) {
    const int t = blockIdx.x * 8 + (threadIdx.x >> 5);   // 0..65535  (b,h,pos)
    const int d = threadIdx.x & 31;
    const int pos = t & 4095;
    const int h = (t >> 12) & 7;
    const int b = t >> 15;
    float s0, c0, s1, c1;
    sincosf(rot[pos * 64 + d], &s0, &c0);
    sincosf(rot[pos * 64 + d + 32], &s1, &c1);
    __bf16* qp = qkv + ((size_t)b * 4096 + pos) * 1536 + h * 64;
    const float qs = 0.125f * LOG2E;
    {
        const float a = (float)qp[d], bb = (float)qp[d + 32];
        qp[d]      = (__bf16)((a * c0 - bb * s0) * qs);
        qp[d + 32] = (__bf16)((bb * c1 + a * s1) * qs);
    }
    __bf16* kp = qp + 512;
    {
        const float a = (float)kp[d], bb = (float)kp[d + 32];
        kp[d]      = (__bf16)(a * c0 - bb * s0);
        kp[d + 32] = (__bf16)(bb * c1 + a * s1);
    }
}

// ---------------------------------------------------------------------------
// Causal flash attention v3: 8 waves (512 thr), 16 q-rows/wave (QBLK=128),
// KVBLK=64, double-buffered K/V with async-stage split (issue loads early,
// ds_write after compute), one barrier per tile.
// S^T = mfma(K, Q): lane owns qrow = l&15; softmax lane-local except
// shfl_xor(16/32). O^T = mfma(V^T, P^T).
// K: [64][72] padded (conflict-free). V^T: [64][64] with column-block XOR
// swizzle cb' = cb ^ f(row), f(r) = ((r>>1)&7) ^ ((r&1)<<2)  -> conflict-free
// for even-row writes, odd-row writes, and 16-row frag reads.
// ---------------------------------------------------------------------------
__global__ __launch_bounds__(512, 4) void attn_kernel(const __bf16* __restrict__ qkv,
                                                      __bf16* __restrict__ attn_out) {
    const int bid = blockIdx.x;
    const int swz = (bid & 7) * 64 + (bid >> 3);   // 8 XCDs x 64 chunks
    const int bh  = swz >> 5;                      // 2 heads per XCD
    const int qt  = 31 - (swz & 31);               // heavy blocks first
    const int b = bh >> 3, h = bh & 7;
    const int q0 = qt * 128;
    const int tid = threadIdx.x;
    const int w = tid >> 6, l = tid & 63, lg = l >> 4, lr = l & 15;
    const int wq0 = q0 + 16 * w;

    __shared__ __align__(16) __bf16 Ks[2][64 * 72];
    __shared__ __align__(16) __bf16 Vt[2][64 * 64];
    __shared__ __align__(16) __bf16 Pl[8][16][72];

    const size_t rs = 1536;
    const __bf16* qbase = qkv + (size_t)b * 4096 * rs + h * 64;
    const __bf16* kbase = qbase + 512;
    const __bf16* vbase = qbase + 1024;

    // Q B-frags for this wave's 16 rows
    bf16x8 Qf[2];
#pragma unroll
    for (int kh = 0; kh < 2; ++kh)
        Qf[kh] = *reinterpret_cast<const bf16x8*>(
            qbase + (size_t)(wq0 + lr) * rs + 32 * kh + 8 * lg);

    f32x4 O[4] = {};                 // O^T[d=16dt+4lg+r][qrow=lr]
    float m_ = -1e30f, l_ = 0.0f;
    const int fl = ((lr >> 1) & 7) ^ ((lr & 1) << 2);   // V swizzle at read rows

    // staging assignments
    const int krow = tid >> 3, kcol8 = tid & 7;         // K: all 512 threads
    const bool vstg = tid < 256;                        // V: first 256 threads
    const int vd2 = (tid & 31) * 2, vjc = (tid >> 5) & 7;
    const int vfa = (vd2 >> 1) & 7, vfb = vfa ^ 4;

    bf16x8 kreg;
    uint vreg[8];

    auto stage_load = [&](int kt2) {
        const int k0n = kt2 * 64;
        kreg = *reinterpret_cast<const bf16x8*>(kbase + (size_t)(k0n + krow) * rs + kcol8 * 8);
        if (vstg) {
            const __bf16* vp = vbase + (size_t)(k0n + 8 * vjc) * rs + vd2;
#pragma unroll
            for (int q = 0; q < 8; ++q)
                vreg[q] = *reinterpret_cast<const uint*>(vp + (size_t)q * rs);
        }
    };
    auto stage_write = [&](int nx) {
        *reinterpret_cast<bf16x8*>(&Ks[nx][krow * 72 + kcol8 * 8]) = kreg;
        if (vstg) {
            union { __bf16 h[8]; bf16x8 v; } ra, rb;
            union { uint u; __bf16 h[2]; } sp;
#pragma unroll
            for (int q = 0; q < 8; ++q) {
                sp.u = vreg[q];
                ra.h[q] = sp.h[0];
                rb.h[q] = sp.h[1];
            }
            *reinterpret_cast<bf16x8*>(&Vt[nx][vd2 * 64 + ((vjc ^ vfa) * 8)])       = ra.v;
            *reinterpret_cast<bf16x8*>(&Vt[nx][(vd2 + 1) * 64 + ((vjc ^ vfb) * 8)]) = rb.v;
        }
    };

    const int nkt = 2 * qt + 2;
    stage_load(0);
    stage_write(0);
    __syncthreads();

    for (int kt = 0; kt < nkt; ++kt) {
        const int cur = kt & 1;
        const int k0 = kt * 64;
        const bool more = (kt + 1 < nkt);
        if (more) stage_load(kt + 1);            // issue early: latency hides under compute

        if (k0 <= wq0 + 15) {
            // ---- S^T = K @ Q ----
            f32x4 S[4] = {};
#pragma unroll
            for (int jt = 0; jt < 4; ++jt) {
                const bf16x8 Kf0 = *reinterpret_cast<const bf16x8*>(&Ks[cur][(16 * jt + lr) * 72 + 8 * lg]);
                const bf16x8 Kf1 = *reinterpret_cast<const bf16x8*>(&Ks[cur][(16 * jt + lr) * 72 + 32 + 8 * lg]);
                S[jt] = __builtin_amdgcn_mfma_f32_16x16x32_bf16(Kf0, Qf[0], S[jt], 0, 0, 0);
                S[jt] = __builtin_amdgcn_mfma_f32_16x16x32_bf16(Kf1, Qf[1], S[jt], 0, 0, 0);
            }
            const int qrow = wq0 + lr;
            if (k0 + 63 > wq0) {                 // diagonal tile: mask
#pragma unroll
                for (int jt = 0; jt < 4; ++jt)
#pragma unroll
                    for (int r = 0; r < 4; ++r)
                        if (k0 + 16 * jt + 4 * lg + r > qrow) S[jt][r] = -1e30f;
            }
            // online softmax (exp2 domain; log2e folded into q)
            float mx = -1e30f;
#pragma unroll
            for (int jt = 0; jt < 4; ++jt)
                mx = fmaxf(mx, fmaxf(fmaxf(S[jt][0], S[jt][1]), fmaxf(S[jt][2], S[jt][3])));
            mx = fmaxf(mx, __shfl_xor(mx, 16));
            mx = fmaxf(mx, __shfl_xor(mx, 32));
            const float mn = fmaxf(m_, mx);
            const float alpha = exp2f(m_ - mn);
            m_ = mn;
            float sum = 0.0f;
#pragma unroll
            for (int jt = 0; jt < 4; ++jt)
#pragma unroll
                for (int r = 0; r < 4; ++r) {
                    S[jt][r] = exp2f(S[jt][r] - mn);
                    sum += S[jt][r];
                }
            sum += __shfl_xor(sum, 16);
            sum += __shfl_xor(sum, 32);
            l_ = l_ * alpha + sum;
#pragma unroll
            for (int dt = 0; dt < 4; ++dt) O[dt] *= alpha;
            // P -> LDS bounce (per-wave buffer)
#pragma unroll
            for (int jt = 0; jt < 4; ++jt) {
                union { __bf16 h[4]; uint2 u; } pw;
#pragma unroll
                for (int r = 0; r < 4; ++r) pw.h[r] = (__bf16)S[jt][r];
                *reinterpret_cast<uint2*>(&Pl[w][lr][16 * jt + 4 * lg]) = pw.u;
            }
            asm volatile("s_waitcnt lgkmcnt(0)" ::: "memory");
            __builtin_amdgcn_sched_barrier(0);
            // O^T += V^T @ P^T
#pragma unroll
            for (int s = 0; s < 2; ++s) {
                const bf16x8 Pf = *reinterpret_cast<const bf16x8*>(&Pl[w][lr][32 * s + 8 * lg]);
#pragma unroll
                for (int dt = 0; dt < 4; ++dt) {
                    const bf16x8 Vf = *reinterpret_cast<const bf16x8*>(
                        &Vt[cur][(16 * dt + lr) * 64 + (((4 * s + lg) ^ fl) * 8)]);
                    O[dt] = __builtin_amdgcn_mfma_f32_16x16x32_bf16(Vf, Pf, O[dt], 0, 0, 0);
                }
            }
        }

        if (more) stage_write(cur ^ 1);          // vmcnt wait lands here, after compute
        __syncthreads();
    }

    // epilogue: attn_out[b][qrow][h*64 + d] = O^T / l   (packed b64 stores)
    const float inv = 1.0f / l_;
    __bf16* op = attn_out + ((size_t)b * 4096 + wq0 + lr) * 512 + h * 64;
#pragma unroll
    for (int dt = 0; dt < 4; ++dt) {
        union { __bf16 h[4]; uint2 u; } ow;
#pragma unroll
        for (int r = 0; r < 4; ++r) ow.h[r] = (__bf16)(O[dt][r] * inv);
        *reinterpret_cast<uint2*>(op + 16 * dt + 4 * lg) = ow.u;
    }
}

// ---------------------------------------------------------------------------
extern "C" void kernel_launch(void* const* d_in, const int* in_sizes, int n_in,
                              void* d_out, int out_size, void* d_ws, size_t ws_size,
                              hipStream_t stream) {
    (void)in_sizes; (void)n_in; (void)out_size; (void)ws_size;
    const float* x    = (const float*)d_in[0];
    const float* rot  = (const float*)d_in[1];
    const float* rmsw = (const float*)d_in[2];
    const float* wqkv = (const float*)d_in[3];
    const float* wout = (const float*)d_in[4];
    float* out = (float*)d_out;

    char* ws = (char*)d_ws;
    __bf16* xn    = (__bf16*)ws;                       // 16,777,216 B
    __bf16* wqkvt = (__bf16*)(ws + 16777216);          //  3,145,728 B
    __bf16* woutt = (__bf16*)(ws + 16777216 + 3145728);//  1,048,576 B
    __bf16* aout  = (__bf16*)(ws + 16777216 + 3145728 + 1048576); // 8,388,608 B
    __bf16* qkv   = (__bf16*)d_out;                    // scratch; overwritten by final GEMM

    rmsnorm_kernel<<<8192, 256, 0, stream>>>(x, rmsw, xn);
    transpose_cast_kernel<<<dim3(48, 32), dim3(32, 8), 0, stream>>>(wqkv, wqkvt, 1024, 1536);
    transpose_cast_kernel<<<dim3(32, 16), dim3(32, 8), 0, stream>>>(wout, woutt, 512, 1024);
    gemm_bt<__bf16><<<dim3(12, 64), 256, 0, stream>>>(xn, wqkvt, qkv, 8192, 1536, 1024);
    rope_kernel<<<8192, 256, 0, stream>>>(qkv, rot);
    attn_kernel<<<512, 512, 0, stream>>>(qkv, aout);
    gemm_bt<float><<<dim3(8, 64), 256, 0, stream>>>(aout, woutt, out, 8192, 1024, 512);
}

// Round 4
// 212.465 us; speedup vs baseline: 2.4215x; 1.1048x over previous
//
#include <hip/hip_runtime.h>
#include <hip/hip_bf16.h>
#include <cstdint>

using bf16x8 = __attribute__((ext_vector_type(8))) __bf16;
using f32x4  = __attribute__((ext_vector_type(4))) float;

#define LOG2E 1.4426950408889634f

__device__ inline void gload16(__bf16* lds, const __bf16* g) {
    __builtin_amdgcn_global_load_lds((const __attribute__((address_space(1))) void*)g,
                                     (__attribute__((address_space(3))) void*)lds, 16, 0, 0);
}

// ---------------------------------------------------------------------------
// RMSNorm: one block (256 threads) per row of 1024 fp32 -> bf16
// ---------------------------------------------------------------------------
__global__ __launch_bounds__(256) void rmsnorm_kernel(const float* __restrict__ x,
                                                      const float* __restrict__ w,
                                                      __bf16* __restrict__ xn) {
    const int row = blockIdx.x;
    const float4 v = reinterpret_cast<const float4*>(x + (size_t)row * 1024)[threadIdx.x];
    float ss = v.x * v.x + v.y * v.y + v.z * v.z + v.w * v.w;
#pragma unroll
    for (int i = 1; i < 64; i <<= 1) ss += __shfl_xor(ss, i);
    __shared__ float part[4];
    if ((threadIdx.x & 63) == 0) part[threadIdx.x >> 6] = ss;
    __syncthreads();
    const float total = part[0] + part[1] + part[2] + part[3];
    const float scale = rsqrtf(total * (1.0f / 1024.0f) + 1.1920929e-07f);
    const float4 wv = reinterpret_cast<const float4*>(w)[threadIdx.x];
    union { __bf16 h[4]; uint2 u; } pk;
    pk.h[0] = (__bf16)(v.x * scale * wv.x);
    pk.h[1] = (__bf16)(v.y * scale * wv.y);
    pk.h[2] = (__bf16)(v.z * scale * wv.z);
    pk.h[3] = (__bf16)(v.w * scale * wv.w);
    reinterpret_cast<uint2*>(xn + (size_t)row * 1024)[threadIdx.x] = pk.u;
}

// ---------------------------------------------------------------------------
// Transpose + cast: in (K x N) fp32 row-major -> out (N x K) bf16 row-major
// ---------------------------------------------------------------------------
__global__ void transpose_cast_kernel(const float* __restrict__ in,
                                      __bf16* __restrict__ out, int K, int N) {
    __shared__ float tile[32][33];
    const int n0 = blockIdx.x * 32, k0 = blockIdx.y * 32;
#pragma unroll
    for (int r = threadIdx.y; r < 32; r += 8)
        tile[r][threadIdx.x] = in[(size_t)(k0 + r) * N + n0 + threadIdx.x];
    __syncthreads();
#pragma unroll
    for (int r = threadIdx.y; r < 32; r += 8)
        out[(size_t)(n0 + r) * K + k0 + threadIdx.x] = (__bf16)tile[threadIdx.x][r];
}

// ---------------------------------------------------------------------------
// GEMM: C(MxN) = A(MxK) @ Bt(NxK)^T, bf16 in, fp32 accum.
// 128x128 tile, BK=32, 4 waves, global_load_lds width-16 staging (m97 recipe).
// ---------------------------------------------------------------------------
template <typename OutT>
__global__ __launch_bounds__(256) void gemm_bt(const __bf16* __restrict__ A,
                                               const __bf16* __restrict__ Bt,
                                               OutT* __restrict__ C,
                                               int M, int N, int K) {
    __shared__ __align__(16) __bf16 As[128 * 32];
    __shared__ __align__(16) __bf16 Bs[128 * 32];
    const int bm = blockIdx.y, bn = blockIdx.x;
    const int tid = threadIdx.x;
    const int w = tid >> 6, l = tid & 63, lg = l >> 4, lr = l & 15;
    const int wr = w >> 1, wc = w & 1;
    const __bf16* Ab = A + (size_t)(bm * 128) * K;
    const __bf16* Bb = Bt + (size_t)(bn * 128) * K;
    const int srow = tid >> 2, scol = (tid & 3) * 8;   // thread stages rows srow, srow+64
    f32x4 acc[4][4] = {};
    for (int k0 = 0; k0 < K; k0 += 32) {
        gload16(As + tid * 8,        Ab + (size_t)srow * K + k0 + scol);
        gload16(As + 2048 + tid * 8, Ab + (size_t)(srow + 64) * K + k0 + scol);
        gload16(Bs + tid * 8,        Bb + (size_t)srow * K + k0 + scol);
        gload16(Bs + 2048 + tid * 8, Bb + (size_t)(srow + 64) * K + k0 + scol);
        __syncthreads();
        bf16x8 af[4], bfr[4];
#pragma unroll
        for (int m = 0; m < 4; ++m)
            af[m] = *reinterpret_cast<const bf16x8*>(&As[(wr * 64 + m * 16 + lr) * 32 + lg * 8]);
#pragma unroll
        for (int nn = 0; nn < 4; ++nn)
            bfr[nn] = *reinterpret_cast<const bf16x8*>(&Bs[(wc * 64 + nn * 16 + lr) * 32 + lg * 8]);
#pragma unroll
        for (int m = 0; m < 4; ++m)
#pragma unroll
            for (int nn = 0; nn < 4; ++nn)
                acc[m][nn] = __builtin_amdgcn_mfma_f32_16x16x32_bf16(af[m], bfr[nn],
                                                                     acc[m][nn], 0, 0, 0);
        __syncthreads();
    }
#pragma unroll
    for (int m = 0; m < 4; ++m) {
        const int rg = bm * 128 + wr * 64 + m * 16 + 4 * lg;
#pragma unroll
        for (int nn = 0; nn < 4; ++nn) {
            const int cg = bn * 128 + wc * 64 + nn * 16 + lr;
#pragma unroll
            for (int r = 0; r < 4; ++r)
                C[(size_t)(rg + r) * N + cg] = (OutT)acc[m][nn][r];
        }
    }
}

// ---------------------------------------------------------------------------
// RoPE in-place on qkv [8192][1536]; q also scaled by d^-0.5 * log2(e)
// ---------------------------------------------------------------------------
__global__ __launch_bounds__(256) void rope_kernel(__bf16* __restrict__ qkv,
                                                   const float* __restrict__ rot) {
    const int t = blockIdx.x * 8 + (threadIdx.x >> 5);   // (b,h,pos)
    const int d = threadIdx.x & 31;
    const int pos = t & 4095;
    const int h = (t >> 12) & 7;
    const int b = t >> 15;
    float s0, c0, s1, c1;
    sincosf(rot[pos * 64 + d], &s0, &c0);
    sincosf(rot[pos * 64 + d + 32], &s1, &c1);
    __bf16* qp = qkv + ((size_t)b * 4096 + pos) * 1536 + h * 64;
    const float qs = 0.125f * LOG2E;
    {
        const float a = (float)qp[d], bb = (float)qp[d + 32];
        qp[d]      = (__bf16)((a * c0 - bb * s0) * qs);
        qp[d + 32] = (__bf16)((bb * c1 + a * s1) * qs);
    }
    __bf16* kp = qp + 512;
    {
        const float a = (float)kp[d], bb = (float)kp[d + 32];
        kp[d]      = (__bf16)(a * c0 - bb * s0);
        kp[d + 32] = (__bf16)(bb * c1 + a * s1);
    }
}

// ---------------------------------------------------------------------------
// Causal flash attention v4: two-tile software pipeline.
// 8 waves (512 thr), 16 q-rows/wave (QBLK=128), KVBLK=64, dbuf K/V.
// Body(t): issue loads(t+2); QK(t+1) [MFMA, overlaps softmax(t) VALU];
// softmax(t) with defer-max; PV(t); barrier; stage_write(t+2); barrier.
// ---------------------------------------------------------------------------
__global__ __launch_bounds__(512) void attn_kernel(const __bf16* __restrict__ qkv,
                                                   __bf16* __restrict__ attn_out) {
    const int bid = blockIdx.x;
    const int swz = (bid & 7) * 64 + (bid >> 3);   // 8 XCDs x 64 chunks
    const int bh  = swz >> 5;                      // 2 heads per XCD
    const int qt  = 31 - (swz & 31);               // heavy blocks first
    const int b = bh >> 3, h = bh & 7;
    const int q0 = qt * 128;
    const int tid = threadIdx.x;
    const int w = tid >> 6, l = tid & 63, lg = l >> 4, lr = l & 15;
    const int wq0 = q0 + 16 * w;

    __shared__ __align__(16) __bf16 Ks[2][64 * 72];
    __shared__ __align__(16) __bf16 Vt[2][64 * 64];
    __shared__ __align__(16) __bf16 Pl[8][16][72];

    const size_t rs = 1536;
    const __bf16* qbase = qkv + (size_t)b * 4096 * rs + h * 64;
    const __bf16* kbase = qbase + 512;
    const __bf16* vbase = qbase + 1024;

    bf16x8 Qf[2];
#pragma unroll
    for (int kh = 0; kh < 2; ++kh)
        Qf[kh] = *reinterpret_cast<const bf16x8*>(
            qbase + (size_t)(wq0 + lr) * rs + 32 * kh + 8 * lg);

    f32x4 O[4] = {};
    float m_ = -1e30f, l_ = 0.0f;
    const int fl = ((lr >> 1) & 7) ^ ((lr & 1) << 2);   // V swizzle at read rows

    const int krow = tid >> 3, kcol8 = tid & 7;
    const bool vstg = tid < 256;
    const int vd2 = (tid & 31) * 2, vjc = (tid >> 5) & 7;
    const int vfa = (vd2 >> 1) & 7, vfb = vfa ^ 4;

    bf16x8 kreg;
    uint vreg[8];

    auto stage_load = [&](int kt2) {
        const int k0n = kt2 * 64;
        kreg = *reinterpret_cast<const bf16x8*>(kbase + (size_t)(k0n + krow) * rs + kcol8 * 8);
        if (vstg) {
            const __bf16* vp = vbase + (size_t)(k0n + 8 * vjc) * rs + vd2;
#pragma unroll
            for (int q = 0; q < 8; ++q)
                vreg[q] = *reinterpret_cast<const uint*>(vp + (size_t)q * rs);
        }
    };
    auto stage_write = [&](int nx) {
        *reinterpret_cast<bf16x8*>(&Ks[nx][krow * 72 + kcol8 * 8]) = kreg;
        if (vstg) {
            union { __bf16 h[8]; bf16x8 v; } ra, rb;
            union { uint u; __bf16 h[2]; } sp;
#pragma unroll
            for (int q = 0; q < 8; ++q) {
                sp.u = vreg[q];
                ra.h[q] = sp.h[0];
                rb.h[q] = sp.h[1];
            }
            *reinterpret_cast<bf16x8*>(&Vt[nx][vd2 * 64 + ((vjc ^ vfa) * 8)])       = ra.v;
            *reinterpret_cast<bf16x8*>(&Vt[nx][(vd2 + 1) * 64 + ((vjc ^ vfb) * 8)]) = rb.v;
        }
    };
    auto qk = [&](f32x4* S, int bufi) {
#pragma unroll
        for (int jt = 0; jt < 4; ++jt) {
            const bf16x8 Kf0 = *reinterpret_cast<const bf16x8*>(&Ks[bufi][(16 * jt + lr) * 72 + 8 * lg]);
            const bf16x8 Kf1 = *reinterpret_cast<const bf16x8*>(&Ks[bufi][(16 * jt + lr) * 72 + 32 + 8 * lg]);
            S[jt] = __builtin_amdgcn_mfma_f32_16x16x32_bf16(Kf0, Qf[0], S[jt], 0, 0, 0);
            S[jt] = __builtin_amdgcn_mfma_f32_16x16x32_bf16(Kf1, Qf[1], S[jt], 0, 0, 0);
        }
    };

    const int nkt = 2 * qt + 2;

    // prologue: tiles 0 and 1 staged; S_prev = QK(0)
    stage_load(0);
    stage_write(0);
    stage_load(1);
    __syncthreads();
    f32x4 Sp[4] = {};
    qk(Sp, 0);
    stage_write(1);
    __syncthreads();

    for (int t = 0; t < nkt; ++t) {
        const int cur = t & 1;
        const bool more2 = (t + 2 < nkt);
        if (more2) stage_load(t + 2);

        f32x4 Sn[4] = {};
        const bool act_n = (t + 1 < nkt) && (64 * (t + 1) <= wq0 + 15);
        if (act_n) qk(Sn, cur ^ 1);

        if (64 * t <= wq0 + 15) {
            const int k0 = 64 * t;
            const int qrow = wq0 + lr;
            if (k0 + 63 > wq0) {                 // diagonal tile: mask
#pragma unroll
                for (int jt = 0; jt < 4; ++jt)
#pragma unroll
                    for (int r = 0; r < 4; ++r)
                        if (k0 + 16 * jt + 4 * lg + r > qrow) Sp[jt][r] = -1e30f;
            }
            float mx = -1e30f;
#pragma unroll
            for (int jt = 0; jt < 4; ++jt)
                mx = fmaxf(mx, fmaxf(fmaxf(Sp[jt][0], Sp[jt][1]), fmaxf(Sp[jt][2], Sp[jt][3])));
            mx = fmaxf(mx, __shfl_xor(mx, 16));
            mx = fmaxf(mx, __shfl_xor(mx, 32));
            if (__any(mx > m_ + 8.0f)) {         // defer-max: rescale only on growth
                const float mn = fmaxf(m_, mx);
                const float alpha = __builtin_amdgcn_exp2f(m_ - mn);
                m_ = mn;
                l_ *= alpha;
#pragma unroll
                for (int dt = 0; dt < 4; ++dt) O[dt] *= alpha;
            }
            float sum = 0.0f;
#pragma unroll
            for (int jt = 0; jt < 4; ++jt)
#pragma unroll
                for (int r = 0; r < 4; ++r) {
                    const float p = __builtin_amdgcn_exp2f(Sp[jt][r] - m_);
                    Sp[jt][r] = p;
                    sum += p;
                }
            sum += __shfl_xor(sum, 16);
            sum += __shfl_xor(sum, 32);
            l_ += sum;
#pragma unroll
            for (int jt = 0; jt < 4; ++jt) {
                union { __bf16 h[4]; uint2 u; } pw;
#pragma unroll
                for (int r = 0; r < 4; ++r) pw.h[r] = (__bf16)Sp[jt][r];
                *reinterpret_cast<uint2*>(&Pl[w][lr][16 * jt + 4 * lg]) = pw.u;
            }
            asm volatile("s_waitcnt lgkmcnt(0)" ::: "memory");
            __builtin_amdgcn_sched_barrier(0);
#pragma unroll
            for (int s = 0; s < 2; ++s) {
                const bf16x8 Pf = *reinterpret_cast<const bf16x8*>(&Pl[w][lr][32 * s + 8 * lg]);
#pragma unroll
                for (int dt = 0; dt < 4; ++dt) {
                    const bf16x8 Vf = *reinterpret_cast<const bf16x8*>(
                        &Vt[cur][(16 * dt + lr) * 64 + (((4 * s + lg) ^ fl) * 8)]);
                    O[dt] = __builtin_amdgcn_mfma_f32_16x16x32_bf16(Vf, Pf, O[dt], 0, 0, 0);
                }
            }
        }

        __syncthreads();                          // all reads of buf cur done
        if (more2) {
            stage_write(cur);                     // tile t+2 -> buf cur
            __syncthreads();                      // publish
        }
#pragma unroll
        for (int jt = 0; jt < 4; ++jt) Sp[jt] = Sn[jt];
    }

    const float inv = 1.0f / l_;
    __bf16* op = attn_out + ((size_t)b * 4096 + wq0 + lr) * 512 + h * 64;
#pragma unroll
    for (int dt = 0; dt < 4; ++dt) {
        union { __bf16 h[4]; uint2 u; } ow;
#pragma unroll
        for (int r = 0; r < 4; ++r) ow.h[r] = (__bf16)(O[dt][r] * inv);
        *reinterpret_cast<uint2*>(op + 16 * dt + 4 * lg) = ow.u;
    }
}

// ---------------------------------------------------------------------------
extern "C" void kernel_launch(void* const* d_in, const int* in_sizes, int n_in,
                              void* d_out, int out_size, void* d_ws, size_t ws_size,
                              hipStream_t stream) {
    (void)in_sizes; (void)n_in; (void)out_size; (void)ws_size;
    const float* x    = (const float*)d_in[0];
    const float* rot  = (const float*)d_in[1];
    const float* rmsw = (const float*)d_in[2];
    const float* wqkv = (const float*)d_in[3];
    const float* wout = (const float*)d_in[4];
    float* out = (float*)d_out;

    char* ws = (char*)d_ws;
    __bf16* xn    = (__bf16*)ws;                       // 16,777,216 B
    __bf16* wqkvt = (__bf16*)(ws + 16777216);          //  3,145,728 B
    __bf16* woutt = (__bf16*)(ws + 16777216 + 3145728);//  1,048,576 B
    __bf16* aout  = (__bf16*)(ws + 16777216 + 3145728 + 1048576); // 8,388,608 B
    __bf16* qkv   = (__bf16*)d_out;                    // scratch; overwritten by final GEMM

    rmsnorm_kernel<<<8192, 256, 0, stream>>>(x, rmsw, xn);
    transpose_cast_kernel<<<dim3(48, 32), dim3(32, 8), 0, stream>>>(wqkv, wqkvt, 1024, 1536);
    transpose_cast_kernel<<<dim3(32, 16), dim3(32, 8), 0, stream>>>(wout, woutt, 512, 1024);
    gemm_bt<__bf16><<<dim3(12, 64), 256, 0, stream>>>(xn, wqkvt, qkv, 8192, 1536, 1024);
    rope_kernel<<<8192, 256, 0, stream>>>(qkv, rot);
    attn_kernel<<<512, 512, 0, stream>>>(qkv, aout);
    gemm_bt<float><<<dim3(8, 64), 256, 0, stream>>>(aout, woutt, out, 8192, 1024, 512);
}

// Round 5
// 177.787 us; speedup vs baseline: 2.8938x; 1.1951x over previous
//
#include <hip/hip_runtime.h>
#include <hip/hip_bf16.h>
#include <cstdint>

using bf16x8 = __attribute__((ext_vector_type(8))) __bf16;
using f32x4  = __attribute__((ext_vector_type(4))) float;

#define LOG2E 1.4426950408889634f

__device__ inline void gload16(__bf16* lds, const __bf16* g) {
    __builtin_amdgcn_global_load_lds((const __attribute__((address_space(1))) void*)g,
                                     (__attribute__((address_space(3))) void*)lds, 16, 0, 0);
}

// ---------------------------------------------------------------------------
// RMSNorm: one block (256 threads) per row of 1024 fp32 -> bf16
// ---------------------------------------------------------------------------
__global__ __launch_bounds__(256) void rmsnorm_kernel(const float* __restrict__ x,
                                                      const float* __restrict__ w,
                                                      __bf16* __restrict__ xn) {
    const int row = blockIdx.x;
    const float4 v = reinterpret_cast<const float4*>(x + (size_t)row * 1024)[threadIdx.x];
    float ss = v.x * v.x + v.y * v.y + v.z * v.z + v.w * v.w;
#pragma unroll
    for (int i = 1; i < 64; i <<= 1) ss += __shfl_xor(ss, i);
    __shared__ float part[4];
    if ((threadIdx.x & 63) == 0) part[threadIdx.x >> 6] = ss;
    __syncthreads();
    const float total = part[0] + part[1] + part[2] + part[3];
    const float scale = rsqrtf(total * (1.0f / 1024.0f) + 1.1920929e-07f);
    const float4 wv = reinterpret_cast<const float4*>(w)[threadIdx.x];
    union { __bf16 h[4]; uint2 u; } pk;
    pk.h[0] = (__bf16)(v.x * scale * wv.x);
    pk.h[1] = (__bf16)(v.y * scale * wv.y);
    pk.h[2] = (__bf16)(v.z * scale * wv.z);
    pk.h[3] = (__bf16)(v.w * scale * wv.w);
    reinterpret_cast<uint2*>(xn + (size_t)row * 1024)[threadIdx.x] = pk.u;
}

// ---------------------------------------------------------------------------
// Transpose + cast: in (K x N) fp32 row-major -> out (N x K) bf16 row-major
// ---------------------------------------------------------------------------
__global__ void transpose_cast_kernel(const float* __restrict__ in,
                                      __bf16* __restrict__ out, int K, int N) {
    __shared__ float tile[32][33];
    const int n0 = blockIdx.x * 32, k0 = blockIdx.y * 32;
#pragma unroll
    for (int r = threadIdx.y; r < 32; r += 8)
        tile[r][threadIdx.x] = in[(size_t)(k0 + r) * N + n0 + threadIdx.x];
    __syncthreads();
#pragma unroll
    for (int r = threadIdx.y; r < 32; r += 8)
        out[(size_t)(n0 + r) * K + k0 + threadIdx.x] = (__bf16)tile[threadIdx.x][r];
}

// ---------------------------------------------------------------------------
// GEMM: C(MxN) = A(MxK) @ Bt(NxK)^T, bf16 in, fp32 accum.
// 128x128 tile, BK=32, 4 waves, global_load_lds width-16 staging (m97 recipe).
// ---------------------------------------------------------------------------
template <typename OutT>
__global__ __launch_bounds__(256) void gemm_bt(const __bf16* __restrict__ A,
                                               const __bf16* __restrict__ Bt,
                                               OutT* __restrict__ C,
                                               int M, int N, int K) {
    __shared__ __align__(16) __bf16 As[128 * 32];
    __shared__ __align__(16) __bf16 Bs[128 * 32];
    const int bm = blockIdx.y, bn = blockIdx.x;
    const int tid = threadIdx.x;
    const int w = tid >> 6, l = tid & 63, lg = l >> 4, lr = l & 15;
    const int wr = w >> 1, wc = w & 1;
    const __bf16* Ab = A + (size_t)(bm * 128) * K;
    const __bf16* Bb = Bt + (size_t)(bn * 128) * K;
    const int srow = tid >> 2, scol = (tid & 3) * 8;
    f32x4 acc[4][4] = {};
    for (int k0 = 0; k0 < K; k0 += 32) {
        gload16(As + tid * 8,        Ab + (size_t)srow * K + k0 + scol);
        gload16(As + 2048 + tid * 8, Ab + (size_t)(srow + 64) * K + k0 + scol);
        gload16(Bs + tid * 8,        Bb + (size_t)srow * K + k0 + scol);
        gload16(Bs + 2048 + tid * 8, Bb + (size_t)(srow + 64) * K + k0 + scol);
        __syncthreads();
        bf16x8 af[4], bfr[4];
#pragma unroll
        for (int m = 0; m < 4; ++m)
            af[m] = *reinterpret_cast<const bf16x8*>(&As[(wr * 64 + m * 16 + lr) * 32 + lg * 8]);
#pragma unroll
        for (int nn = 0; nn < 4; ++nn)
            bfr[nn] = *reinterpret_cast<const bf16x8*>(&Bs[(wc * 64 + nn * 16 + lr) * 32 + lg * 8]);
#pragma unroll
        for (int m = 0; m < 4; ++m)
#pragma unroll
            for (int nn = 0; nn < 4; ++nn)
                acc[m][nn] = __builtin_amdgcn_mfma_f32_16x16x32_bf16(af[m], bfr[nn],
                                                                     acc[m][nn], 0, 0, 0);
        __syncthreads();
    }
#pragma unroll
    for (int m = 0; m < 4; ++m) {
        const int rg = bm * 128 + wr * 64 + m * 16 + 4 * lg;
#pragma unroll
        for (int nn = 0; nn < 4; ++nn) {
            const int cg = bn * 128 + wc * 64 + nn * 16 + lr;
#pragma unroll
            for (int r = 0; r < 4; ++r)
                C[(size_t)(rg + r) * N + cg] = (OutT)acc[m][nn][r];
        }
    }
}

// ---------------------------------------------------------------------------
// RoPE in-place on qkv [8192][1536]; q also scaled by d^-0.5 * log2(e)
// ---------------------------------------------------------------------------
__global__ __launch_bounds__(256) void rope_kernel(__bf16* __restrict__ qkv,
                                                   const float* __restrict__ rot) {
    const int t = blockIdx.x * 8 + (threadIdx.x >> 5);   // (b,h,pos)
    const int d = threadIdx.x & 31;
    const int pos = t & 4095;
    const int h = (t >> 12) & 7;
    const int b = t >> 15;
    float s0, c0, s1, c1;
    sincosf(rot[pos * 64 + d], &s0, &c0);
    sincosf(rot[pos * 64 + d + 32], &s1, &c1);
    __bf16* qp = qkv + ((size_t)b * 4096 + pos) * 1536 + h * 64;
    const float qs = 0.125f * LOG2E;
    {
        const float a = (float)qp[d], bb = (float)qp[d + 32];
        qp[d]      = (__bf16)((a * c0 - bb * s0) * qs);
        qp[d + 32] = (__bf16)((bb * c1 + a * s1) * qs);
    }
    __bf16* kp = qp + 512;
    {
        const float a = (float)kp[d], bb = (float)kp[d + 32];
        kp[d]      = (__bf16)(a * c0 - bb * s0);
        kp[d + 32] = (__bf16)(bb * c1 + a * s1);
    }
}

// ---------------------------------------------------------------------------
// Causal flash attention v5: key-permuted V (P stays in registers),
// deferred cross-lane reductions, 3-buffer ring (1 barrier/tile).
// 8 waves (512 thr), 16 q-rows/wave (QBLK=128), KVBLK=64.
// S^T = mfma(K, Q): lane holds S at key-positions 16jt+4lg+r for qrow=lr.
// V^T stored with column permutation sigma^-1 so PV's B-operand
// (keys 32s+8lg+i) = lane-local pack {Sp[2s],Sp[2s+1]}.
// V swizzle: 4-elem blocks, cb' = cb ^ ((row>>1)&15).
// ---------------------------------------------------------------------------
__global__ __launch_bounds__(512) void attn_kernel(const __bf16* __restrict__ qkv,
                                                   __bf16* __restrict__ attn_out) {
    const int bid = blockIdx.x;
    const int swz = (bid & 7) * 64 + (bid >> 3);   // 8 XCDs x 64 chunks
    const int bh  = swz >> 5;                      // 2 heads per XCD
    const int qt  = 31 - (swz & 31);               // heavy blocks first
    const int b = bh >> 3, h = bh & 7;
    const int q0 = qt * 128;
    const int tid = threadIdx.x;
    const int w = tid >> 6, l = tid & 63, lg = l >> 4, lr = l & 15;
    const int wq0 = q0 + 16 * w;

    __shared__ __align__(16) __bf16 Ks[3][64 * 72];
    __shared__ __align__(16) __bf16 Vt[3][64 * 64];

    const size_t rs = 1536;
    const __bf16* qbase = qkv + (size_t)b * 4096 * rs + h * 64;
    const __bf16* kbase = qbase + 512;
    const __bf16* vbase = qbase + 1024;

    bf16x8 Qf[2];
#pragma unroll
    for (int kh = 0; kh < 2; ++kh)
        Qf[kh] = *reinterpret_cast<const bf16x8*>(
            qbase + (size_t)(wq0 + lr) * rs + 32 * kh + 8 * lg);

    f32x4 O[4] = {};
    float m_ = -1e30f, l_ = 0.0f;

    // staging assignments
    const int krow = tid >> 3, kcol8 = tid & 7;
    const bool vstg = tid < 256;
    const int vd2 = (tid & 31) * 2, vjc = tid >> 5;
    // sigma^-1 column bases for this thread's 8 V rows (4-aligned)
    const int vbase1 = 32 * (vjc >> 2) + 8 * ((2 * vjc) & 3) + ((vjc >> 1) & 1) * 4;
    const int vcb1 = vbase1 >> 2, vcb2 = vcb1 + 2;
    const int g4w = (vd2 >> 1) & 15;

    bf16x8 kreg;
    uint vreg[8];

    auto stage_load = [&](int kt2) {
        const int k0n = kt2 * 64;
        kreg = *reinterpret_cast<const bf16x8*>(kbase + (size_t)(k0n + krow) * rs + kcol8 * 8);
        if (vstg) {
            const __bf16* vp = vbase + (size_t)(k0n + 8 * vjc) * rs + vd2;
#pragma unroll
            for (int q = 0; q < 8; ++q)
                vreg[q] = *reinterpret_cast<const uint*>(vp + (size_t)q * rs);
        }
    };
    auto stage_write = [&](int nx) {
        *reinterpret_cast<bf16x8*>(&Ks[nx][krow * 72 + kcol8 * 8]) = kreg;
        if (vstg) {
            union { uint u; __bf16 h[2]; } sp;
            union { __bf16 h[4]; uint2 u; } wa, wb, wc2, wd;
#pragma unroll
            for (int q = 0; q < 4; ++q) {
                sp.u = vreg[q];      wa.h[q] = sp.h[0]; wc2.h[q] = sp.h[1];
                sp.u = vreg[q + 4];  wb.h[q] = sp.h[0]; wd.h[q]  = sp.h[1];
            }
            __bf16* vrow0 = &Vt[nx][vd2 * 64];
            *reinterpret_cast<uint2*>(vrow0 + ((vcb1 ^ g4w) << 2))      = wa.u;
            *reinterpret_cast<uint2*>(vrow0 + ((vcb2 ^ g4w) << 2))      = wb.u;
            *reinterpret_cast<uint2*>(vrow0 + 64 + ((vcb1 ^ g4w) << 2)) = wc2.u;
            *reinterpret_cast<uint2*>(vrow0 + 64 + ((vcb2 ^ g4w) << 2)) = wd.u;
        }
    };
    auto qk = [&](f32x4* S, int bufi) {
#pragma unroll
        for (int jt = 0; jt < 4; ++jt) {
            const bf16x8 Kf0 = *reinterpret_cast<const bf16x8*>(&Ks[bufi][(16 * jt + lr) * 72 + 8 * lg]);
            const bf16x8 Kf1 = *reinterpret_cast<const bf16x8*>(&Ks[bufi][(16 * jt + lr) * 72 + 32 + 8 * lg]);
            S[jt] = __builtin_amdgcn_mfma_f32_16x16x32_bf16(Kf0, Qf[0], S[jt], 0, 0, 0);
            S[jt] = __builtin_amdgcn_mfma_f32_16x16x32_bf16(Kf1, Qf[1], S[jt], 0, 0, 0);
        }
    };

    const int nkt = 2 * qt + 2;

    // prologue: tiles 0,1 staged into ring bufs 0,1
    stage_load(0);
    stage_write(0);
    stage_load(1);
    stage_write(1);
    __syncthreads();
    f32x4 Sp[4] = {};
    qk(Sp, 0);

    for (int t = 0; t < nkt; ++t) {
        const int bcur = t % 3;
        const bool more2 = (t + 2 < nkt);
        if (more2) stage_load(t + 2);

        f32x4 Sn[4] = {};
        const bool act_n = (t + 1 < nkt) && (64 * (t + 1) <= wq0 + 15);
        if (act_n) qk(Sn, (t + 1) % 3);

        if (64 * t <= wq0 + 15) {
            const int k0 = 64 * t;
            const int qrow = wq0 + lr;
            if (k0 + 63 > wq0) {                 // diagonal tile: mask
#pragma unroll
                for (int jt = 0; jt < 4; ++jt)
#pragma unroll
                    for (int r = 0; r < 4; ++r)
                        if (k0 + 16 * jt + 4 * lg + r > qrow) Sp[jt][r] = -1e30f;
            }
            // lane-local max; cross-lane reduce only on (rare) rescale trigger
            float mx = -1e30f;
#pragma unroll
            for (int jt = 0; jt < 4; ++jt)
                mx = fmaxf(mx, fmaxf(fmaxf(Sp[jt][0], Sp[jt][1]), fmaxf(Sp[jt][2], Sp[jt][3])));
            if (__any(mx > m_ + 8.0f)) {
                mx = fmaxf(mx, __shfl_xor(mx, 16));
                mx = fmaxf(mx, __shfl_xor(mx, 32));
                const float mn = fmaxf(m_, mx);
                const float alpha = __builtin_amdgcn_exp2f(m_ - mn);
                m_ = mn;
                l_ *= alpha;
#pragma unroll
                for (int dt = 0; dt < 4; ++dt) O[dt] *= alpha;
            }
            // exp2 + lane-local l accumulation (row-reduce deferred to epilogue)
            float sum = 0.0f;
#pragma unroll
            for (int jt = 0; jt < 4; ++jt)
#pragma unroll
                for (int r = 0; r < 4; ++r) {
                    const float p = __builtin_amdgcn_exp2f(Sp[jt][r] - m_);
                    Sp[jt][r] = p;
                    sum += p;
                }
            l_ += sum;
            // P pack: lane-local thanks to sigma-permuted V columns
            bf16x8 Pf[2];
#pragma unroll
            for (int s = 0; s < 2; ++s)
#pragma unroll
                for (int i = 0; i < 8; ++i)
                    Pf[s][i] = (__bf16)Sp[2 * s + (i >> 2)][i & 3];
            // O^T += V^T @ P^T   (V frags: two b64 reads, 4-block swizzle)
#pragma unroll
            for (int s = 0; s < 2; ++s)
#pragma unroll
                for (int dt = 0; dt < 4; ++dt) {
                    const int g4 = (lr >> 1) + 8 * (dt & 1);
                    const __bf16* vrow = &Vt[bcur][(16 * dt + lr) * 64];
                    const int cb = 8 * s + 2 * lg;
                    union { uint2 u2[2]; bf16x8 v; } vf;
                    vf.u2[0] = *reinterpret_cast<const uint2*>(vrow + ((cb ^ g4) << 2));
                    vf.u2[1] = *reinterpret_cast<const uint2*>(vrow + (((cb + 1) ^ g4) << 2));
                    O[dt] = __builtin_amdgcn_mfma_f32_16x16x32_bf16(vf.v, Pf[s], O[dt], 0, 0, 0);
                }
        }

        if (more2) stage_write((t + 2) % 3);
        __syncthreads();
#pragma unroll
        for (int jt = 0; jt < 4; ++jt) Sp[jt] = Sn[jt];
    }

    // epilogue: row-sum of l (deferred), then O / l
    l_ += __shfl_xor(l_, 16);
    l_ += __shfl_xor(l_, 32);
    const float inv = 1.0f / l_;
    __bf16* op = attn_out + ((size_t)b * 4096 + wq0 + lr) * 512 + h * 64;
#pragma unroll
    for (int dt = 0; dt < 4; ++dt) {
        union { __bf16 h[4]; uint2 u; } ow;
#pragma unroll
        for (int r = 0; r < 4; ++r) ow.h[r] = (__bf16)(O[dt][r] * inv);
        *reinterpret_cast<uint2*>(op + 16 * dt + 4 * lg) = ow.u;
    }
}

// ---------------------------------------------------------------------------
extern "C" void kernel_launch(void* const* d_in, const int* in_sizes, int n_in,
                              void* d_out, int out_size, void* d_ws, size_t ws_size,
                              hipStream_t stream) {
    (void)in_sizes; (void)n_in; (void)out_size; (void)ws_size;
    const float* x    = (const float*)d_in[0];
    const float* rot  = (const float*)d_in[1];
    const float* rmsw = (const float*)d_in[2];
    const float* wqkv = (const float*)d_in[3];
    const float* wout = (const float*)d_in[4];
    float* out = (float*)d_out;

    char* ws = (char*)d_ws;
    __bf16* xn    = (__bf16*)ws;                       // 16,777,216 B
    __bf16* wqkvt = (__bf16*)(ws + 16777216);          //  3,145,728 B
    __bf16* woutt = (__bf16*)(ws + 16777216 + 3145728);//  1,048,576 B
    __bf16* aout  = (__bf16*)(ws + 16777216 + 3145728 + 1048576); // 8,388,608 B
    __bf16* qkv   = (__bf16*)d_out;                    // scratch; overwritten by final GEMM

    rmsnorm_kernel<<<8192, 256, 0, stream>>>(x, rmsw, xn);
    transpose_cast_kernel<<<dim3(48, 32), dim3(32, 8), 0, stream>>>(wqkv, wqkvt, 1024, 1536);
    transpose_cast_kernel<<<dim3(32, 16), dim3(32, 8), 0, stream>>>(wout, woutt, 512, 1024);
    gemm_bt<__bf16><<<dim3(12, 64), 256, 0, stream>>>(xn, wqkvt, qkv, 8192, 1536, 1024);
    rope_kernel<<<8192, 256, 0, stream>>>(qkv, rot);
    attn_kernel<<<512, 512, 0, stream>>>(qkv, aout);
    gemm_bt<float><<<dim3(8, 64), 256, 0, stream>>>(aout, woutt, out, 8192, 1024, 512);
}

// Round 6
// 164.945 us; speedup vs baseline: 3.1191x; 1.0779x over previous
//
#include <hip/hip_runtime.h>
#include <hip/hip_bf16.h>
#include <cstdint>

using bf16x8 = __attribute__((ext_vector_type(8))) __bf16;
using f32x4  = __attribute__((ext_vector_type(4))) float;

#define LOG2E 1.4426950408889634f

__device__ inline void gload16(__bf16* lds, const __bf16* g) {
    __builtin_amdgcn_global_load_lds((const __attribute__((address_space(1))) void*)g,
                                     (__attribute__((address_space(3))) void*)lds, 16, 0, 0);
}

// ---------------------------------------------------------------------------
// RMSNorm: one block (256 threads) per row of 1024 fp32 -> bf16
// ---------------------------------------------------------------------------
__global__ __launch_bounds__(256) void rmsnorm_kernel(const float* __restrict__ x,
                                                      const float* __restrict__ w,
                                                      __bf16* __restrict__ xn) {
    const int row = blockIdx.x;
    const float4 v = reinterpret_cast<const float4*>(x + (size_t)row * 1024)[threadIdx.x];
    float ss = v.x * v.x + v.y * v.y + v.z * v.z + v.w * v.w;
#pragma unroll
    for (int i = 1; i < 64; i <<= 1) ss += __shfl_xor(ss, i);
    __shared__ float part[4];
    if ((threadIdx.x & 63) == 0) part[threadIdx.x >> 6] = ss;
    __syncthreads();
    const float total = part[0] + part[1] + part[2] + part[3];
    const float scale = rsqrtf(total * (1.0f / 1024.0f) + 1.1920929e-07f);
    const float4 wv = reinterpret_cast<const float4*>(w)[threadIdx.x];
    union { __bf16 h[4]; uint2 u; } pk;
    pk.h[0] = (__bf16)(v.x * scale * wv.x);
    pk.h[1] = (__bf16)(v.y * scale * wv.y);
    pk.h[2] = (__bf16)(v.z * scale * wv.z);
    pk.h[3] = (__bf16)(v.w * scale * wv.w);
    reinterpret_cast<uint2*>(xn + (size_t)row * 1024)[threadIdx.x] = pk.u;
}

// ---------------------------------------------------------------------------
// Transpose + cast: in (K x N) fp32 row-major -> out (N x K) bf16 row-major
// ---------------------------------------------------------------------------
__global__ void transpose_cast_kernel(const float* __restrict__ in,
                                      __bf16* __restrict__ out, int K, int N) {
    __shared__ float tile[32][33];
    const int n0 = blockIdx.x * 32, k0 = blockIdx.y * 32;
#pragma unroll
    for (int r = threadIdx.y; r < 32; r += 8)
        tile[r][threadIdx.x] = in[(size_t)(k0 + r) * N + n0 + threadIdx.x];
    __syncthreads();
#pragma unroll
    for (int r = threadIdx.y; r < 32; r += 8)
        out[(size_t)(n0 + r) * K + k0 + threadIdx.x] = (__bf16)tile[threadIdx.x][r];
}

// ---------------------------------------------------------------------------
// GEMM: C(MxN) = A(MxK) @ Bt(NxK)^T, bf16 in, fp32 accum.
// 128x128 tile, BK=32, 4 waves, global_load_lds width-16 staging (m97 recipe).
// ---------------------------------------------------------------------------
template <typename OutT>
__global__ __launch_bounds__(256) void gemm_bt(const __bf16* __restrict__ A,
                                               const __bf16* __restrict__ Bt,
                                               OutT* __restrict__ C,
                                               int M, int N, int K) {
    __shared__ __align__(16) __bf16 As[128 * 32];
    __shared__ __align__(16) __bf16 Bs[128 * 32];
    const int bm = blockIdx.y, bn = blockIdx.x;
    const int tid = threadIdx.x;
    const int w = tid >> 6, l = tid & 63, lg = l >> 4, lr = l & 15;
    const int wr = w >> 1, wc = w & 1;
    const __bf16* Ab = A + (size_t)(bm * 128) * K;
    const __bf16* Bb = Bt + (size_t)(bn * 128) * K;
    const int srow = tid >> 2, scol = (tid & 3) * 8;
    f32x4 acc[4][4] = {};
    for (int k0 = 0; k0 < K; k0 += 32) {
        gload16(As + tid * 8,        Ab + (size_t)srow * K + k0 + scol);
        gload16(As + 2048 + tid * 8, Ab + (size_t)(srow + 64) * K + k0 + scol);
        gload16(Bs + tid * 8,        Bb + (size_t)srow * K + k0 + scol);
        gload16(Bs + 2048 + tid * 8, Bb + (size_t)(srow + 64) * K + k0 + scol);
        __syncthreads();
        bf16x8 af[4], bfr[4];
#pragma unroll
        for (int m = 0; m < 4; ++m)
            af[m] = *reinterpret_cast<const bf16x8*>(&As[(wr * 64 + m * 16 + lr) * 32 + lg * 8]);
#pragma unroll
        for (int nn = 0; nn < 4; ++nn)
            bfr[nn] = *reinterpret_cast<const bf16x8*>(&Bs[(wc * 64 + nn * 16 + lr) * 32 + lg * 8]);
#pragma unroll
        for (int m = 0; m < 4; ++m)
#pragma unroll
            for (int nn = 0; nn < 4; ++nn)
                acc[m][nn] = __builtin_amdgcn_mfma_f32_16x16x32_bf16(af[m], bfr[nn],
                                                                     acc[m][nn], 0, 0, 0);
        __syncthreads();
    }
#pragma unroll
    for (int m = 0; m < 4; ++m) {
        const int rg = bm * 128 + wr * 64 + m * 16 + 4 * lg;
#pragma unroll
        for (int nn = 0; nn < 4; ++nn) {
            const int cg = bn * 128 + wc * 64 + nn * 16 + lr;
#pragma unroll
            for (int r = 0; r < 4; ++r)
                C[(size_t)(rg + r) * N + cg] = (OutT)acc[m][nn][r];
        }
    }
}

// ---------------------------------------------------------------------------
// RoPE in-place on qkv [8192][1536]; q also scaled by d^-0.5 * log2(e)
// ---------------------------------------------------------------------------
__global__ __launch_bounds__(256) void rope_kernel(__bf16* __restrict__ qkv,
                                                   const float* __restrict__ rot) {
    const int t = blockIdx.x * 8 + (threadIdx.x >> 5);   // (b,h,pos)
    const int d = threadIdx.x & 31;
    const int pos = t & 4095;
    const int h = (t >> 12) & 7;
    const int b = t >> 15;
    float s0, c0, s1, c1;
    sincosf(rot[pos * 64 + d], &s0, &c0);
    sincosf(rot[pos * 64 + d + 32], &s1, &c1);
    __bf16* qp = qkv + ((size_t)b * 4096 + pos) * 1536 + h * 64;
    const float qs = 0.125f * LOG2E;
    {
        const float a = (float)qp[d], bb = (float)qp[d + 32];
        qp[d]      = (__bf16)((a * c0 - bb * s0) * qs);
        qp[d + 32] = (__bf16)((bb * c1 + a * s1) * qs);
    }
    __bf16* kp = qp + 512;
    {
        const float a = (float)kp[d], bb = (float)kp[d + 32];
        kp[d]      = (__bf16)(a * c0 - bb * s0);
        kp[d + 32] = (__bf16)(bb * c1 + a * s1);
    }
}

// ---------------------------------------------------------------------------
// Causal flash attention v6: load-balanced q-tile pairs.
// 256 blocks (1/CU), 512 thr = 8 waves; block handles q-tiles {pr, 31-pr}
// sequentially -> exactly 66 tile-units per block (perfect balance).
// Key-permuted V (P in registers), 3-buffer ring, deferred reductions.
// V^T [64][64] stored in 8B blocks at c^m(row), m(row)=(row^(row>>2))&15:
// 4-way (= structural min) on both staging writes and PV b64 reads.
// Block c = 8s+2lg+b holds actual keys 32s+16b+4lg+{0..3} (kappa perm),
// staged by a-group a = 8s+4b+lg (4 consecutive keys, one d-pair/thread).
// ---------------------------------------------------------------------------
__global__ __launch_bounds__(512) void attn_kernel(const __bf16* __restrict__ qkv,
                                                   __bf16* __restrict__ attn_out) {
    const int bid = blockIdx.x;                      // 256 blocks
    const int bh = 2 * (bid & 7) + ((bid >> 3) >> 4);// 2 heads per XCD
    const int pr = (bid >> 3) & 15;                  // pair id 0..15
    const int b = bh >> 3, h = bh & 7;
    const int tid = threadIdx.x;
    const int w = tid >> 6, l = tid & 63, lg = l >> 4, lr = l & 15;

    __shared__ __align__(16) __bf16 Ks[3][64 * 72];
    __shared__ __align__(16) __bf16 Vt[3][64 * 64];

    const size_t rs = 1536;
    const __bf16* qbase = qkv + (size_t)b * 4096 * rs + h * 64;
    const __bf16* kbase = qbase + 512;
    const __bf16* vbase = qbase + 1024;

    // staging constants
    const int krow = tid >> 3, kcol8 = tid & 7;
    const int va = tid >> 5;                         // a-group 0..15 (4 keys)
    const int vd = (tid & 31) * 2;                   // d-column pair
    const int vca = 8 * (va >> 3) + 2 * (va & 3) + ((va >> 2) & 1);
    const int vm0 = (vd ^ (vd >> 2)) & 15;
    const int vm1 = ((vd + 1) ^ ((vd + 1) >> 2)) & 15;

    bf16x8 kreg;
    uint vreg[4];

    auto stage_load = [&](int kt2) {
        const int k0n = kt2 * 64;
        kreg = *reinterpret_cast<const bf16x8*>(kbase + (size_t)(k0n + krow) * rs + kcol8 * 8);
        const __bf16* vp = vbase + (size_t)(k0n + 4 * va) * rs + vd;
#pragma unroll
        for (int t = 0; t < 4; ++t)
            vreg[t] = *reinterpret_cast<const uint*>(vp + (size_t)t * rs);
    };
    auto stage_write = [&](int nx) {
        *reinterpret_cast<bf16x8*>(&Ks[nx][krow * 72 + kcol8 * 8]) = kreg;
        union { uint u; __bf16 h[2]; } sp;
        union { __bf16 h[4]; uint2 u; } wa, wb;
#pragma unroll
        for (int t = 0; t < 4; ++t) {
            sp.u = vreg[t];
            wa.h[t] = sp.h[0];
            wb.h[t] = sp.h[1];
        }
        *reinterpret_cast<uint2*>(&Vt[nx][vd * 64 + ((vca ^ vm0) << 2)])       = wa.u;
        *reinterpret_cast<uint2*>(&Vt[nx][(vd + 1) * 64 + ((vca ^ vm1) << 2)]) = wb.u;
    };

    for (int seg = 0; seg < 2; ++seg) {
        const int qt = seg ? (31 - pr) : pr;
        const int q0 = qt * 128;
        const int wq0 = q0 + 16 * w;

        bf16x8 Qf[2];
#pragma unroll
        for (int kh = 0; kh < 2; ++kh)
            Qf[kh] = *reinterpret_cast<const bf16x8*>(
                qbase + (size_t)(wq0 + lr) * rs + 32 * kh + 8 * lg);

        auto qk = [&](f32x4* S, int bufi) {
            __builtin_amdgcn_s_setprio(1);
#pragma unroll
            for (int jt = 0; jt < 4; ++jt) {
                const bf16x8 Kf0 = *reinterpret_cast<const bf16x8*>(&Ks[bufi][(16 * jt + lr) * 72 + 8 * lg]);
                const bf16x8 Kf1 = *reinterpret_cast<const bf16x8*>(&Ks[bufi][(16 * jt + lr) * 72 + 32 + 8 * lg]);
                S[jt] = __builtin_amdgcn_mfma_f32_16x16x32_bf16(Kf0, Qf[0], S[jt], 0, 0, 0);
                S[jt] = __builtin_amdgcn_mfma_f32_16x16x32_bf16(Kf1, Qf[1], S[jt], 0, 0, 0);
            }
            __builtin_amdgcn_s_setprio(0);
        };

        f32x4 O[4] = {};
        float m_ = -1e30f, l_ = 0.0f;
        const int nkt = 2 * qt + 2;

        // prologue: stage tiles 0,1 into ring bufs 0,1
        stage_load(0);
        stage_write(0);
        stage_load(1);
        stage_write(1);
        __syncthreads();
        f32x4 Sp[4] = {};
        qk(Sp, 0);

        for (int t = 0; t < nkt; ++t) {
            const int bcur = t % 3;
            const bool more2 = (t + 2 < nkt);
            if (more2) stage_load(t + 2);

            f32x4 Sn[4] = {};
            const bool act_n = (t + 1 < nkt) && (64 * (t + 1) <= wq0 + 15);
            if (act_n) qk(Sn, (t + 1) % 3);

            if (64 * t <= wq0 + 15) {
                const int k0 = 64 * t;
                const int qrow = wq0 + lr;
                if (k0 + 63 > wq0) {                 // diagonal tile: mask
#pragma unroll
                    for (int jt = 0; jt < 4; ++jt)
#pragma unroll
                        for (int r = 0; r < 4; ++r)
                            if (k0 + 16 * jt + 4 * lg + r > qrow) Sp[jt][r] = -1e30f;
                }
                // lane-local max; cross-lane reduce only on (rare) rescale
                float mx = -1e30f;
#pragma unroll
                for (int jt = 0; jt < 4; ++jt)
                    mx = fmaxf(mx, fmaxf(fmaxf(Sp[jt][0], Sp[jt][1]), fmaxf(Sp[jt][2], Sp[jt][3])));
                if (__any(mx > m_ + 8.0f)) {
                    mx = fmaxf(mx, __shfl_xor(mx, 16));
                    mx = fmaxf(mx, __shfl_xor(mx, 32));
                    const float mn = fmaxf(m_, mx);
                    const float alpha = __builtin_amdgcn_exp2f(m_ - mn);
                    m_ = mn;
                    l_ *= alpha;
#pragma unroll
                    for (int dt = 0; dt < 4; ++dt) O[dt] *= alpha;
                }
                float sum = 0.0f;
#pragma unroll
                for (int jt = 0; jt < 4; ++jt)
#pragma unroll
                    for (int r = 0; r < 4; ++r) {
                        const float p = __builtin_amdgcn_exp2f(Sp[jt][r] - m_);
                        Sp[jt][r] = p;
                        sum += p;
                    }
                l_ += sum;
                // P pack (lane-local via kappa-permuted V) + PV
                __builtin_amdgcn_s_setprio(1);
#pragma unroll
                for (int s = 0; s < 2; ++s) {
                    bf16x8 Pf;
#pragma unroll
                    for (int i = 0; i < 8; ++i)
                        Pf[i] = (__bf16)Sp[2 * s + (i >> 2)][i & 3];
#pragma unroll
                    for (int dt = 0; dt < 4; ++dt) {
                        const int row = 16 * dt + lr;
                        const int m = (row ^ (row >> 2)) & 15;
                        const __bf16* vrow = &Vt[bcur][row * 64];
                        const int c0 = 8 * s + 2 * lg;
                        union { uint2 u2[2]; bf16x8 v; } vf;
                        vf.u2[0] = *reinterpret_cast<const uint2*>(vrow + ((c0 ^ m) << 2));
                        vf.u2[1] = *reinterpret_cast<const uint2*>(vrow + (((c0 + 1) ^ m) << 2));
                        O[dt] = __builtin_amdgcn_mfma_f32_16x16x32_bf16(vf.v, Pf, O[dt], 0, 0, 0);
                    }
                }
                __builtin_amdgcn_s_setprio(0);
            }

            if (more2) stage_write((t + 2) % 3);
            __syncthreads();
#pragma unroll
            for (int jt = 0; jt < 4; ++jt) Sp[jt] = Sn[jt];
        }

        // epilogue: deferred row-sum of l, then O / l
        float lt = l_;
        lt += __shfl_xor(lt, 16);
        lt += __shfl_xor(lt, 32);
        const float inv = 1.0f / lt;
        __bf16* op = attn_out + ((size_t)b * 4096 + wq0 + lr) * 512 + h * 64;
#pragma unroll
        for (int dt = 0; dt < 4; ++dt) {
            union { __bf16 h[4]; uint2 u; } ow;
#pragma unroll
            for (int r = 0; r < 4; ++r) ow.h[r] = (__bf16)(O[dt][r] * inv);
            *reinterpret_cast<uint2*>(op + 16 * dt + 4 * lg) = ow.u;
        }
    }
}

// ---------------------------------------------------------------------------
extern "C" void kernel_launch(void* const* d_in, const int* in_sizes, int n_in,
                              void* d_out, int out_size, void* d_ws, size_t ws_size,
                              hipStream_t stream) {
    (void)in_sizes; (void)n_in; (void)out_size; (void)ws_size;
    const float* x    = (const float*)d_in[0];
    const float* rot  = (const float*)d_in[1];
    const float* rmsw = (const float*)d_in[2];
    const float* wqkv = (const float*)d_in[3];
    const float* wout = (const float*)d_in[4];
    float* out = (float*)d_out;

    char* ws = (char*)d_ws;
    __bf16* xn    = (__bf16*)ws;                       // 16,777,216 B
    __bf16* wqkvt = (__bf16*)(ws + 16777216);          //  3,145,728 B
    __bf16* woutt = (__bf16*)(ws + 16777216 + 3145728);//  1,048,576 B
    __bf16* aout  = (__bf16*)(ws + 16777216 + 3145728 + 1048576); // 8,388,608 B
    __bf16* qkv   = (__bf16*)d_out;                    // scratch; overwritten by final GEMM

    rmsnorm_kernel<<<8192, 256, 0, stream>>>(x, rmsw, xn);
    transpose_cast_kernel<<<dim3(48, 32), dim3(32, 8), 0, stream>>>(wqkv, wqkvt, 1024, 1536);
    transpose_cast_kernel<<<dim3(32, 16), dim3(32, 8), 0, stream>>>(wout, woutt, 512, 1024);
    gemm_bt<__bf16><<<dim3(12, 64), 256, 0, stream>>>(xn, wqkvt, qkv, 8192, 1536, 1024);
    rope_kernel<<<8192, 256, 0, stream>>>(qkv, rot);
    attn_kernel<<<256, 512, 0, stream>>>(qkv, aout);
    gemm_bt<float><<<dim3(8, 64), 256, 0, stream>>>(aout, woutt, out, 8192, 1024, 512);
}